// Round 14
// baseline (586.745 us; speedup 1.0000x reference)
//
#include <hip/hip_runtime.h>

#define N_OUT   128
#define IN_DIM  128
#define EDGE_D  16
#define TILE    128
#define TILE_N  64
#define NKG_E   18    // edge kgroups of 8 k (144 exact)
#define NKG_N   32    // node kgroups (256 k)

#define EBUF    (NKG_E*TILE*16)        // 36864 B per sA half
#define EBUFSZ  (2*EBUF + TILE*4)      // 74240 B per buffer (sAh+sAl+sDst)

typedef short  s16x8  __attribute__((ext_vector_type(8)));
typedef float  f32x4  __attribute__((ext_vector_type(4)));
typedef float  f32x16 __attribute__((ext_vector_type(16)));

__device__ __forceinline__ ushort f2bf(float f) {
    unsigned u = __float_as_uint(f);
    return (ushort)((u + 0x7FFFu + ((u >> 16) & 1u)) >> 16);   // RNE
}
__device__ __forceinline__ float bf2f(ushort h) {
    return __uint_as_float(((unsigned)h) << 16);
}

// async global->LDS DMA: dest = wave-uniform LDS base + lane*size
__device__ __forceinline__ void gld16(const void* g, void* l) {
    __builtin_amdgcn_global_load_lds((const __attribute__((address_space(1))) void*)g,
                                     (__attribute__((address_space(3))) void*)l, 16, 0, 0);
}
__device__ __forceinline__ void gld4(const void* g, void* l) {
    __builtin_amdgcn_global_load_lds((const __attribute__((address_space(1))) void*)g,
                                     (__attribute__((address_space(3))) void*)l, 4, 0, 0);
}

// 32x32 MFMA C/D layout: col=lane&31, row=(reg&3)+8*(reg>>2)+4*(lane>>5).
// Storage perm within each 32-row subtile so lane (h=lane>>5) owns 16
// CONSECUTIVE sorted positions: pos = h*16 + q*4 + r <-> row = q*8 + h*4 + r.
__device__ __forceinline__ int perm_slot(int pos) {   // sorted pos -> storage slot
    int i = pos & 31;                                  // bits: [4]=h [3:2]=q [1:0]=r
    int s = ((i & 0x0C) << 1) | ((i & 0x10) >> 2) | (i & 3);
    return (pos & ~31) | s;
}
__device__ __forceinline__ int inv_slot(int s) {       // storage slot -> sorted pos
    int i = s & 31;                                    // bits: [4:3]=q [2]=h [1:0]=r
    int pos = ((i & 0x04) << 2) | ((i & 0x18) >> 1) | (i & 3);
    return (s & ~31) | pos;
}

// ---------------- one-time prep ----------------
__global__ void split_kernel(const float* __restrict__ x, ushort* __restrict__ xh,
                             ushort* __restrict__ xl, int n) {
    int i = blockIdx.x * blockDim.x + threadIdx.x;
    if (i < n) {
        float f = x[i];
        ushort h = f2bf(f);
        xh[i] = h;
        xl[i] = f2bf(f - bf2f(h));
    }
}

// W [K][128] f32 -> hi/lo bf16 in MFMA B-frag layout: [(k/8)*128 + col]*8 + (k&7)
__global__ void wprep_kernel(const float* __restrict__ W, ushort* __restrict__ Whf,
                             ushort* __restrict__ Wlf, int K) {
    int i = blockIdx.x * blockDim.x + threadIdx.x;
    if (i >= K * N_OUT) return;
    int k = i >> 7, col = i & 127;
    float f = W[k * N_OUT + col];
    ushort h = f2bf(f);
    int d = ((k >> 3) * N_OUT + col) * 8 + (k & 7);
    Whf[d] = h;
    Wlf[d] = f2bf(f - bf2f(h));
}

// permuted + split edge_attr, indexed by STORAGE slot (pad slots -> zeros)
__global__ void eaprep_kernel(const float* __restrict__ ea, const int* __restrict__ eperm,
                              ushort* __restrict__ eah, ushort* __restrict__ eal,
                              int nE, int nP) {
    int t2 = blockIdx.x * blockDim.x + threadIdx.x;
    int s = t2 >> 1, half = t2 & 1;
    if (s >= nP) return;
    int p = inv_slot(s);
    s16x8 hv = {0,0,0,0,0,0,0,0}, lv = {0,0,0,0,0,0,0,0};
    if (p < nE) {
        int e = eperm[s];
        const float4* src = (const float4*)(ea + (size_t)e * EDGE_D + half * 8);
        float4 v0 = src[0], v1 = src[1];
        float a[8] = {v0.x, v0.y, v0.z, v0.w, v1.x, v1.y, v1.z, v1.w};
        #pragma unroll
        for (int j = 0; j < 8; ++j) {
            ushort h = f2bf(a[j]);
            hv[j] = (short)h;
            lv[j] = (short)f2bf(a[j] - bf2f(h));
        }
    }
    *(s16x8*)(eah + (size_t)s * EDGE_D + half * 8) = hv;
    *(s16x8*)(eal + (size_t)s * EDGE_D + half * 8) = lv;
}

// ---------------- CSR build (once; src/dst are layer-invariant) ----------------
__global__ void hist_kernel(const int* __restrict__ dst, int* __restrict__ hist, int nE) {
    int e = blockIdx.x * blockDim.x + threadIdx.x;
    if (e < nE) atomicAdd(&hist[dst[e]], 1);
}

__global__ void scan1_kernel(const int* __restrict__ hist, int* __restrict__ incl,
                             int* __restrict__ bsum, int n) {
    __shared__ int buf[1024];
    int i = blockIdx.x * 1024 + threadIdx.x;
    int v = (i < n) ? hist[i] : 0;
    buf[threadIdx.x] = v;
    __syncthreads();
    for (int off = 1; off < 1024; off <<= 1) {
        int t = (threadIdx.x >= (unsigned)off) ? buf[threadIdx.x - off] : 0;
        __syncthreads();
        buf[threadIdx.x] += t;
        __syncthreads();
    }
    if (i < n) incl[i] = buf[threadIdx.x];
    if (threadIdx.x == 1023) bsum[blockIdx.x] = buf[1023];
}
__global__ void scan2_kernel(int* __restrict__ bsum, int nb) {
    if (threadIdx.x == 0 && blockIdx.x == 0) {
        int run = 0;
        for (int i = 0; i < nb; ++i) { int t = bsum[i]; bsum[i] = run; run += t; }
    }
}
__global__ void scan3_kernel(const int* __restrict__ incl, const int* __restrict__ hist,
                             const int* __restrict__ bsum, int* __restrict__ rowptr, int n) {
    int i = blockIdx.x * blockDim.x + threadIdx.x;
    if (i < n) rowptr[i] = incl[i] - hist[i] + bsum[i >> 10];   // exclusive
}

// writes edge data at PERMUTED storage slot (pad slots pre-filled by memset)
__global__ void scatter_kernel(const int* __restrict__ src, const int* __restrict__ dst,
                               const int* __restrict__ rowptr, int* __restrict__ cursor,
                               int* __restrict__ eperm, int* __restrict__ srcS,
                               int* __restrict__ dstS, int nE) {
    int e = blockIdx.x * blockDim.x + threadIdx.x;
    if (e < nE) {
        int d = dst[e];
        int pos = rowptr[d] + atomicAdd(&cursor[d], 1);
        int s = perm_slot(pos);
        eperm[s] = e;
        dstS[s]  = d;
        srcS[s]  = src[e];
    }
}

__global__ void deg_kernel(const int* __restrict__ hist, float* __restrict__ cntf, int n) {
    int i = blockIdx.x * blockDim.x + threadIdx.x;
    if (i < n) cntf[i] = (float)hist[i];
}

// ---------------- edge GEMM: 32x32x16 MFMA (2x FLOP per LDS byte), 1024-thread ----------------
// ---------------- block (4 waves/SIMD), DMA double-buffer, 1 barrier/tile,     ----------------
// ---------------- K=144 = 9 exact k-steps, lane-local 16-pos segmented reduce  ----------------
__global__ __launch_bounds__(1024, 4) void edge_mfma_kernel(
    const ushort* __restrict__ xh, const ushort* __restrict__ xl,
    const int*   __restrict__ srcS,
    const int*   __restrict__ dstS,
    const ushort* __restrict__ eah, const ushort* __restrict__ eal,
    const ushort* __restrict__ Whf, const ushort* __restrict__ Wlf,
    const float* __restrict__ bias,
    float* __restrict__ agg,     // pre-zeroed
    int nTiles)
{
    __shared__ __align__(16) char smem[2 * EBUFSZ];   // 148480 B (1 block/CU)

    const int tid  = threadIdx.x;
    const int w    = tid >> 6;        // 0..15
    const int lane = tid & 63;
    const int h    = lane >> 5;       // k-half within a k-step of 16
    const int cl   = lane & 31;       // col within col-group / row within row-tile
    const int cg   = w & 3;           // col group: cols cg*32 .. cg*32+31
    const int rt   = w >> 2;          // row tile: rows rt*32 .. rt*32+31
    const int row  = tid & 127;       // staging row this thread covers
    const int c    = w >> 1;          // 0..7 staging k-eighth (wave-uniform)
    const int row0 = (w & 1) * 64;    // wave-uniform row base for DMA dests
    const int nP = nTiles * TILE;

    // B fragments: 9 k-steps x (hi,lo) x 4 VGPRs = 72 regs
    s16x8 Bh[9], Bl[9];
    #pragma unroll
    for (int kg = 0; kg < 9; ++kg) {
        int kg8 = kg * 2 + h;
        int colb = cg * 32 + cl;
        Bh[kg] = *(const s16x8*)&Whf[(kg8 * N_OUT + colb) * 8];
        Bl[kg] = *(const s16x8*)&Wlf[(kg8 * N_OUT + colb) * 8];
    }
    const float bv = bias[cg * 32 + cl];
    const int G = gridDim.x;

    // stage tile into `bufb` via DMA (fragment layout, lane x 16B)
    auto stage = [&](char* bufb, int sv, int pp) {
        ushort* bAh  = (ushort*)bufb;
        ushort* bAl  = (ushort*)(bufb + EBUF);
        int*    bDst = (int*)(bufb + 2*EBUF);
        if (c < 4) {
            #pragma unroll
            for (int g = 0; g < 4; ++g) {
                int kg = c*4 + g;
                gld16(xh + (size_t)sv*IN_DIM + c*32 + g*8, &bAh[(kg*TILE + row0)*8]);
            }
            // edge_attr: c selects (kgroup 16/17) x (hi/lo); pre-permuted, contiguous
            const ushort* es = (c & 2) ? eal : eah;
            ushort* bd       = (c & 2) ? bAl : bAh;
            int kg = 16 + (c & 1);
            gld16(es + (size_t)pp*EDGE_D + (c & 1)*8, &bd[(kg*TILE + row0)*8]);
        } else {
            int cq = c - 4;
            #pragma unroll
            for (int g = 0; g < 4; ++g) {
                int kg = cq*4 + g;
                gld16(xl + (size_t)sv*IN_DIM + cq*32 + g*8, &bAl[(kg*TILE + row0)*8]);
            }
        }
        if (tid < 128) gld4(dstS + pp, bDst + row0);
    };

    // ---- prologue ----
    const int t0 = blockIdx.x;
    stage(smem, srcS[t0 * TILE + row], t0 * TILE + row);
    int srcNext = srcS[min((t0 + G) * TILE + row, nP - 1)];
    __syncthreads();   // drains prologue DMA

    int cur = 0;
    for (int t = t0; t < nTiles; t += G) {
        char* bufc = smem + cur * EBUFSZ;
        char* bufn = smem + (cur ^ 1) * EBUFSZ;

        // ---- stage next tile (overlaps MFMA; drained at the barrier) ----
        if (t + G < nTiles) stage(bufn, srcNext, (t + G) * TILE + row);
        srcNext = srcS[min((t + 2*G) * TILE + row, nP - 1)];

        const ushort* cAh  = (const ushort*)bufc;
        const ushort* cAl  = (const ushort*)(bufc + EBUF);
        const int*    cDst = (const int*)(bufc + 2*EBUF);

        f32x16 acc;
        #pragma unroll
        for (int j = 0; j < 16; ++j) acc[j] = bv;

        // ---- MFMA: 9 k-steps x 3 products; one A hi/lo pair feeds 3 MFMAs ----
        #pragma unroll
        for (int kg = 0; kg < 9; ++kg) {
            const int base = ((kg*2 + h) * TILE + rt*32 + cl) * 8;
            s16x8 ah = *(const s16x8*)&cAh[base];
            s16x8 al = *(const s16x8*)&cAl[base];
            acc = __builtin_amdgcn_mfma_f32_32x32x16_bf16(ah, Bh[kg], acc, 0, 0, 0);
            acc = __builtin_amdgcn_mfma_f32_32x32x16_bf16(al, Bh[kg], acc, 0, 0, 0);
            acc = __builtin_amdgcn_mfma_f32_32x32x16_bf16(ah, Bl[kg], acc, 0, 0, 0);
        }

        // ---- lane-local segmented reduce over 16 consecutive sorted positions ----
        // lane holds rows q*8 + h*4 + r (q=0..3, r=0..3) = sorted pos h*16 + q*4 + r;
        // value for pos j is acc[j] directly. Interior runs globally unique -> store;
        // open first/last runs -> atomicAdd.
        {
            float* aggc = agg + cg * 32 + cl;
            int4 dd[4];
            #pragma unroll
            for (int q = 0; q < 4; ++q)
                dd[q] = *(const int4*)&cDst[rt*32 + q*8 + h*4];

            int cd = dd[0].x;
            float c0 = fmaxf(acc[0], 0.0f);
            bool firstRun = true;
            #pragma unroll
            for (int j = 1; j < 16; ++j) {
                const int d = ((const int*)&dd[j >> 2])[j & 3];
                const float u = fmaxf(acc[j], 0.0f);
                if (d == cd) {
                    c0 += u;
                } else {
                    if (cd >= 0) {
                        if (firstRun) atomicAdd(aggc + (size_t)cd * N_OUT, c0);
                        else          aggc[(size_t)cd * N_OUT] = c0;
                    }
                    firstRun = false;
                    cd = d; c0 = u;
                }
            }
            if (cd >= 0) atomicAdd(aggc + (size_t)cd * N_OUT, c0);
        }

        __syncthreads();   // drains next-tile DMA + closes WAR on bufn
        cur ^= 1;
    }
}

// ---------------- node update (split-bf16 MFMA): relu(concat(h, agg/cnt) @ U) ----------------
__global__ __launch_bounds__(512, 2) void node_mfma_kernel(
    const ushort* __restrict__ hh, const ushort* __restrict__ hl,
    const float* __restrict__ agg, const float* __restrict__ cnt,
    const ushort* __restrict__ Uhf, const ushort* __restrict__ Ulf,
    float* __restrict__ outf, ushort* __restrict__ outh, ushort* __restrict__ outl,
    int lastLayer, int nNodes)
{
    __shared__ __align__(16) ushort sAh[NKG_N * TILE_N * 8];   // 32768 B
    __shared__ __align__(16) ushort sAl[NKG_N * TILE_N * 8];   // 32768 B

    const int tid  = threadIdx.x;
    const int w    = tid >> 6;
    const int lane = tid & 63;
    const int lg   = lane >> 4;
    const int lr   = lane & 15;
    const int col  = w * 16 + lr;
    const int tile = blockIdx.x;
    const int row  = lane;          // 0..63
    const int c    = w;             // 0..7 k-eighth

    s16x8 Bh[8], Bl[8];
    #pragma unroll
    for (int kb = 0; kb < 8; ++kb) {
        int kg = kb * 4 + lg;
        Bh[kb] = *(const s16x8*)&Uhf[(kg * N_OUT + col) * 8];
        Bl[kb] = *(const s16x8*)&Ulf[(kg * N_OUT + col) * 8];
    }

    const int ii = min(tile * TILE_N + row, nNodes - 1);
    if (c < 4) {   // h part: kg 0..15, pure DMA copy
        #pragma unroll
        for (int g = 0; g < 4; ++g) {
            int kg = c*4 + g;
            gld16(hh + (size_t)ii*N_OUT + c*32 + g*8, &sAh[(kg*TILE_N)*8]);
            gld16(hl + (size_t)ii*N_OUT + c*32 + g*8, &sAl[(kg*TILE_N)*8]);
        }
    } else {       // agg part: scale by 1/deg, split
        float rc = 1.0f / fmaxf(cnt[ii], 1.0f);
        const float4* pa = (const float4*)(agg + (size_t)ii*N_OUT + (c - 4)*32);
        #pragma unroll
        for (int g = 0; g < 4; ++g) {
            float4 v0 = pa[g*2], v1 = pa[g*2 + 1];
            float a[8] = {v0.x, v0.y, v0.z, v0.w, v1.x, v1.y, v1.z, v1.w};
            s16x8 hv, lv;
            #pragma unroll
            for (int j = 0; j < 8; ++j) {
                float f = a[j] * rc;
                ushort h = f2bf(f);
                hv[j] = (short)h;
                lv[j] = (short)f2bf(f - bf2f(h));
            }
            int kg = 16 + (c - 4)*4 + g;
            *(s16x8*)&sAh[(kg*TILE_N + row)*8] = hv;
            *(s16x8*)&sAl[(kg*TILE_N + row)*8] = lv;
        }
    }
    __syncthreads();

    f32x4 acc[4];
    #pragma unroll
    for (int b = 0; b < 4; ++b) acc[b] = (f32x4){0.f, 0.f, 0.f, 0.f};

    #pragma unroll
    for (int kb = 0; kb < 8; ++kb) {
        #pragma unroll
        for (int b = 0; b < 4; ++b) {
            const int base = ((kb*4 + lg) * TILE_N + b*16 + lr) * 8;
            s16x8 ah = *(const s16x8*)&sAh[base];
            s16x8 al = *(const s16x8*)&sAl[base];
            acc[b] = __builtin_amdgcn_mfma_f32_16x16x32_bf16(ah, Bh[kb], acc[b], 0, 0, 0);
            acc[b] = __builtin_amdgcn_mfma_f32_16x16x32_bf16(al, Bh[kb], acc[b], 0, 0, 0);
            acc[b] = __builtin_amdgcn_mfma_f32_16x16x32_bf16(ah, Bl[kb], acc[b], 0, 0, 0);
        }
    }

    #pragma unroll
    for (int b = 0; b < 4; ++b) {
        #pragma unroll
        for (int r = 0; r < 4; ++r) {
            int rr = tile * TILE_N + b*16 + lg*4 + r;
            if (rr < nNodes) {
                float v = fmaxf(acc[b][r], 0.0f);
                if (lastLayer) {
                    outf[(size_t)rr * N_OUT + col] = v;
                } else {
                    ushort h = f2bf(v);
                    outh[(size_t)rr * N_OUT + col] = h;
                    outl[(size_t)rr * N_OUT + col] = f2bf(v - bf2f(h));
                }
            }
        }
    }
}

extern "C" void kernel_launch(void* const* d_in, const int* in_sizes, int n_in,
                              void* d_out, int out_size, void* d_ws, size_t ws_size,
                              hipStream_t stream)
{
    const float* x  = (const float*)d_in[0];
    const int*   ei = (const int*)  d_in[1];
    const float* ea = (const float*)d_in[2];
    const float* W1 = (const float*)d_in[3];
    const float* b1 = (const float*)d_in[4];
    const float* U1 = (const float*)d_in[5];
    const float* W2 = (const float*)d_in[6];
    const float* b2 = (const float*)d_in[7];
    const float* U2 = (const float*)d_in[8];

    const int nE      = in_sizes[1] / 2;
    const int nNodes  = in_sizes[0] / IN_DIM;
    const int nTilesE = (nE + TILE - 1) / TILE;
    const int nP      = nTilesE * TILE;
    const int nTilesN = (nNodes + TILE_N - 1) / TILE_N;
    const int nSB     = (nNodes + 1023) / 1024;
    const int* srcp = ei;
    const int* dstp = ei + nE;

    char* p = (char*)d_ws;
    auto alloc = [&](size_t bytes) { void* r = (void*)p; p += (bytes + 255) & ~(size_t)255; return r; };

    float*  agg   = (float*) alloc((size_t)nNodes * N_OUT * sizeof(float));
    ushort* xhh   = (ushort*)alloc((size_t)nNodes * N_OUT * sizeof(ushort));
    ushort* xll   = (ushort*)alloc((size_t)nNodes * N_OUT * sizeof(ushort));
    float*  cntf  = (float*) alloc((size_t)nNodes * sizeof(float));
    int*    hist  = (int*)   alloc((size_t)nNodes * sizeof(int));
    int*    incl  = (int*)   alloc((size_t)nNodes * sizeof(int));
    int*    bsum  = (int*)   alloc((size_t)(nSB + 1) * sizeof(int));
    int*    rowptr= (int*)   alloc((size_t)(nNodes + 1) * sizeof(int));
    int*    cursor= (int*)   alloc((size_t)nNodes * sizeof(int));
    int*    eperm = (int*)   alloc((size_t)nP * sizeof(int));
    int*    dstS  = (int*)   alloc((size_t)nP * sizeof(int));
    int*    srcS  = (int*)   alloc((size_t)nP * sizeof(int));
    ushort* eah   = (ushort*)alloc((size_t)nP * EDGE_D * sizeof(ushort));
    ushort* eal   = (ushort*)alloc((size_t)nP * EDGE_D * sizeof(ushort));
    ushort* Whf1  = (ushort*)alloc((size_t)NKG_E * 8 * N_OUT * sizeof(ushort));
    ushort* Wlf1  = (ushort*)alloc((size_t)NKG_E * 8 * N_OUT * sizeof(ushort));
    ushort* Whf2  = (ushort*)alloc((size_t)NKG_E * 8 * N_OUT * sizeof(ushort));
    ushort* Wlf2  = (ushort*)alloc((size_t)NKG_E * 8 * N_OUT * sizeof(ushort));
    ushort* Uhf1  = (ushort*)alloc((size_t)NKG_N * 8 * N_OUT * sizeof(ushort));
    ushort* Ulf1  = (ushort*)alloc((size_t)NKG_N * 8 * N_OUT * sizeof(ushort));
    ushort* Uhf2  = (ushort*)alloc((size_t)NKG_N * 8 * N_OUT * sizeof(ushort));
    ushort* Ulf2  = (ushort*)alloc((size_t)NKG_N * 8 * N_OUT * sizeof(ushort));
    float*  outp  = (float*)d_out;

    // ---- one-time prep: CSR, permuted storage, degree, split ea/x, weight frags ----
    hipMemsetAsync(hist,   0,    (size_t)nNodes * sizeof(int), stream);
    hipMemsetAsync(cursor, 0,    (size_t)nNodes * sizeof(int), stream);
    hipMemsetAsync(srcS,   0,    (size_t)nP * sizeof(int), stream);       // pad: node 0
    hipMemsetAsync(dstS,   0xFF, (size_t)nP * sizeof(int), stream);       // pad: dst -1
    hist_kernel<<<(nE + 255)/256, 256, 0, stream>>>(dstp, hist, nE);
    scan1_kernel<<<nSB, 1024, 0, stream>>>(hist, incl, bsum, nNodes);
    scan2_kernel<<<1, 64, 0, stream>>>(bsum, nSB);
    scan3_kernel<<<(nNodes + 255)/256, 256, 0, stream>>>(incl, hist, bsum, rowptr, nNodes);
    scatter_kernel<<<(nE + 255)/256, 256, 0, stream>>>(srcp, dstp, rowptr, cursor,
                                                       eperm, srcS, dstS, nE);
    deg_kernel<<<(nNodes + 255)/256, 256, 0, stream>>>(hist, cntf, nNodes);
    eaprep_kernel<<<(2*nP + 255)/256, 256, 0, stream>>>(ea, eperm, eah, eal, nE, nP);
    wprep_kernel<<<(NKG_E*8*N_OUT + 255)/256, 256, 0, stream>>>(W1, Whf1, Wlf1, NKG_E*8);
    wprep_kernel<<<(NKG_E*8*N_OUT + 255)/256, 256, 0, stream>>>(W2, Whf2, Wlf2, NKG_E*8);
    wprep_kernel<<<(NKG_N*8*N_OUT + 255)/256, 256, 0, stream>>>(U1, Uhf1, Ulf1, NKG_N*8);
    wprep_kernel<<<(NKG_N*8*N_OUT + 255)/256, 256, 0, stream>>>(U2, Uhf2, Ulf2, NKG_N*8);
    split_kernel<<<((nNodes*N_OUT) + 255)/256, 256, 0, stream>>>(x, xhh, xll, nNodes * IN_DIM);

    auto run_layer = [&](const ushort* Whf, const ushort* Wlf, const float* b,
                         const ushort* Uhf, const ushort* Ulf, int last) {
        hipMemsetAsync(agg, 0, (size_t)nNodes * N_OUT * sizeof(float), stream);
        edge_mfma_kernel<<<256, 1024, 0, stream>>>(xhh, xll, srcS, dstS, eah, eal,
                                                   Whf, Wlf, b, agg, nTilesE);
        node_mfma_kernel<<<nTilesN, 512, 0, stream>>>(xhh, xll, agg, cntf, Uhf, Ulf,
                                                      outp, xhh, xll, last, nNodes);
    };

    run_layer(Whf1, Wlf1, b1, Uhf1, Ulf1, 0);   // conv1 -> (xhh,xll)
    run_layer(Whf2, Wlf2, b2, Uhf2, Ulf2, 0);   // conv2 -> (xhh,xll)
    run_layer(Whf2, Wlf2, b2, Uhf2, Ulf2, 1);   // conv3 -> d_out (f32)
}

// Round 15
// 552.632 us; speedup vs baseline: 1.0617x; 1.0617x over previous
//
#include <hip/hip_runtime.h>

#define N_OUT   128
#define IN_DIM  128
#define EDGE_D  16
#define TILE    128
#define TILE_N  64
#define NKG_E   18    // edge kgroups of 8 k (144 exact)
#define NKG_N   32    // node kgroups (256 k)

#define EBUF    (NKG_E*TILE*16)        // 36864 B per sA half
#define EBUFSZ  (2*EBUF + TILE*4)      // 74240 B per buffer (sAh+sAl+sDst)

typedef short  s16x8  __attribute__((ext_vector_type(8)));
typedef float  f32x4  __attribute__((ext_vector_type(4)));
typedef float  f32x16 __attribute__((ext_vector_type(16)));

__device__ __forceinline__ ushort f2bf(float f) {
    unsigned u = __float_as_uint(f);
    return (ushort)((u + 0x7FFFu + ((u >> 16) & 1u)) >> 16);   // RNE
}
__device__ __forceinline__ float bf2f(ushort h) {
    return __uint_as_float(((unsigned)h) << 16);
}

// async global->LDS DMA: dest = wave-uniform LDS base + lane*size; src is per-lane
__device__ __forceinline__ void gld16(const void* g, void* l) {
    __builtin_amdgcn_global_load_lds((const __attribute__((address_space(1))) void*)g,
                                     (__attribute__((address_space(3))) void*)l, 16, 0, 0);
}
__device__ __forceinline__ void gld4(const void* g, void* l) {
    __builtin_amdgcn_global_load_lds((const __attribute__((address_space(1))) void*)g,
                                     (__attribute__((address_space(3))) void*)l, 4, 0, 0);
}

// 32x32 MFMA C/D layout: col=lane&31, row=(reg&3)+8*(reg>>2)+4*(lane>>5).
// Storage perm within each 32-row subtile so lane (h=lane>>5) owns 16
// CONSECUTIVE sorted positions: pos = h*16 + q*4 + r <-> row = q*8 + h*4 + r.
__device__ __forceinline__ int perm_slot(int pos) {   // sorted pos -> storage slot
    int i = pos & 31;                                  // bits: [4]=h [3:2]=q [1:0]=r
    int s = ((i & 0x0C) << 1) | ((i & 0x10) >> 2) | (i & 3);
    return (pos & ~31) | s;
}
__device__ __forceinline__ int inv_slot(int s) {       // storage slot -> sorted pos
    int i = s & 31;                                    // bits: [4:3]=q [2]=h [1:0]=r
    int pos = ((i & 0x04) << 2) | ((i & 0x18) >> 1) | (i & 3);
    return (s & ~31) | pos;
}

// ---------------- one-time prep ----------------
__global__ void split_kernel(const float* __restrict__ x, ushort* __restrict__ xh,
                             ushort* __restrict__ xl, int n) {
    int i = blockIdx.x * blockDim.x + threadIdx.x;
    if (i < n) {
        float f = x[i];
        ushort h = f2bf(f);
        xh[i] = h;
        xl[i] = f2bf(f - bf2f(h));
    }
}

// W [K][128] f32 -> hi/lo bf16 in MFMA B-frag layout: [(k/8)*128 + col]*8 + (k&7)
__global__ void wprep_kernel(const float* __restrict__ W, ushort* __restrict__ Whf,
                             ushort* __restrict__ Wlf, int K) {
    int i = blockIdx.x * blockDim.x + threadIdx.x;
    if (i >= K * N_OUT) return;
    int k = i >> 7, col = i & 127;
    float f = W[k * N_OUT + col];
    ushort h = f2bf(f);
    int d = ((k >> 3) * N_OUT + col) * 8 + (k & 7);
    Whf[d] = h;
    Wlf[d] = f2bf(f - bf2f(h));
}

// permuted + split edge_attr, indexed by STORAGE slot (pad slots -> zeros)
__global__ void eaprep_kernel(const float* __restrict__ ea, const int* __restrict__ eperm,
                              ushort* __restrict__ eah, ushort* __restrict__ eal,
                              int nE, int nP) {
    int t2 = blockIdx.x * blockDim.x + threadIdx.x;
    int s = t2 >> 1, half = t2 & 1;
    if (s >= nP) return;
    int p = inv_slot(s);
    s16x8 hv = {0,0,0,0,0,0,0,0}, lv = {0,0,0,0,0,0,0,0};
    if (p < nE) {
        int e = eperm[s];
        const float4* src = (const float4*)(ea + (size_t)e * EDGE_D + half * 8);
        float4 v0 = src[0], v1 = src[1];
        float a[8] = {v0.x, v0.y, v0.z, v0.w, v1.x, v1.y, v1.z, v1.w};
        #pragma unroll
        for (int j = 0; j < 8; ++j) {
            ushort h = f2bf(a[j]);
            hv[j] = (short)h;
            lv[j] = (short)f2bf(a[j] - bf2f(h));
        }
    }
    *(s16x8*)(eah + (size_t)s * EDGE_D + half * 8) = hv;
    *(s16x8*)(eal + (size_t)s * EDGE_D + half * 8) = lv;
}

// ---------------- CSR build (once; src/dst are layer-invariant) ----------------
__global__ void hist_kernel(const int* __restrict__ dst, int* __restrict__ hist, int nE) {
    int e = blockIdx.x * blockDim.x + threadIdx.x;
    if (e < nE) atomicAdd(&hist[dst[e]], 1);
}

__global__ void scan1_kernel(const int* __restrict__ hist, int* __restrict__ incl,
                             int* __restrict__ bsum, int n) {
    __shared__ int buf[1024];
    int i = blockIdx.x * 1024 + threadIdx.x;
    int v = (i < n) ? hist[i] : 0;
    buf[threadIdx.x] = v;
    __syncthreads();
    for (int off = 1; off < 1024; off <<= 1) {
        int t = (threadIdx.x >= (unsigned)off) ? buf[threadIdx.x - off] : 0;
        __syncthreads();
        buf[threadIdx.x] += t;
        __syncthreads();
    }
    if (i < n) incl[i] = buf[threadIdx.x];
    if (threadIdx.x == 1023) bsum[blockIdx.x] = buf[1023];
}
__global__ void scan2_kernel(int* __restrict__ bsum, int nb) {
    if (threadIdx.x == 0 && blockIdx.x == 0) {
        int run = 0;
        for (int i = 0; i < nb; ++i) { int t = bsum[i]; bsum[i] = run; run += t; }
    }
}
__global__ void scan3_kernel(const int* __restrict__ incl, const int* __restrict__ hist,
                             const int* __restrict__ bsum, int* __restrict__ rowptr, int n) {
    int i = blockIdx.x * blockDim.x + threadIdx.x;
    if (i < n) rowptr[i] = incl[i] - hist[i] + bsum[i >> 10];   // exclusive
}

// writes edge data at PERMUTED storage slot (pad slots pre-filled by memset)
__global__ void scatter_kernel(const int* __restrict__ src, const int* __restrict__ dst,
                               const int* __restrict__ rowptr, int* __restrict__ cursor,
                               int* __restrict__ eperm, int* __restrict__ srcS,
                               int* __restrict__ dstS, int nE) {
    int e = blockIdx.x * blockDim.x + threadIdx.x;
    if (e < nE) {
        int d = dst[e];
        int pos = rowptr[d] + atomicAdd(&cursor[d], 1);
        int s = perm_slot(pos);
        eperm[s] = e;
        dstS[s]  = d;
        srcS[s]  = src[e];
    }
}

__global__ void deg_kernel(const int* __restrict__ hist, float* __restrict__ cntf, int n) {
    int i = blockIdx.x * blockDim.x + threadIdx.x;
    if (i < n) cntf[i] = (float)hist[i];
}

// ---------------- edge GEMM: 32x32x16 MFMA, 8 waves = 2cg(64col) x 4rt(32row): ----------------
// ---------------- LDS reads 144 b128/tile (vs 640), B-regs 144 fit (512,2)=256 ----------------
// ---------------- budget. DMA double-buffer, 1 barrier/tile, POST-barrier reduce ---------------
__global__ __launch_bounds__(512, 2) void edge_mfma_kernel(
    const ushort* __restrict__ xh, const ushort* __restrict__ xl,
    const int*   __restrict__ srcS,
    const int*   __restrict__ dstS,
    const ushort* __restrict__ eah, const ushort* __restrict__ eal,
    const ushort* __restrict__ Whf, const ushort* __restrict__ Wlf,
    const float* __restrict__ bias,
    float* __restrict__ agg,     // pre-zeroed
    int nTiles)
{
    __shared__ __align__(16) char smem[2 * EBUFSZ];   // 148480 B (1 block/CU)

    const int tid  = threadIdx.x;
    const int w    = tid >> 6;        // 0..7
    const int lane = tid & 63;
    const int h    = lane >> 5;       // k-half within a k-step of 16
    const int cl   = lane & 31;       // col within coltile / row within row-tile
    const int cg   = w & 1;           // col group: cols cg*64 .. cg*64+63 (2 coltiles)
    const int rt   = w >> 1;          // row tile: rows rt*32 .. rt*32+31
    const int nP = nTiles * TILE;

    // B fragments: 9 k-steps x (hi,lo) x 2 coltiles x 4 VGPRs = 144 regs
    s16x8 Bh[9][2], Bl[9][2];
    #pragma unroll
    for (int kg = 0; kg < 9; ++kg) {
        #pragma unroll
        for (int ct = 0; ct < 2; ++ct) {
            int colb = cg * 64 + ct * 32 + cl;
            Bh[kg][ct] = *(const s16x8*)&Whf[((kg*2 + h) * N_OUT + colb) * 8];
            Bl[kg][ct] = *(const s16x8*)&Wlf[((kg*2 + h) * N_OUT + colb) * 8];
        }
    }
    const float bv0 = bias[cg * 64 + cl];
    const float bv1 = bias[cg * 64 + 32 + cl];
    const int G = gridDim.x;

    // stage tile into `bufb` via DMA. Wave w: k-eighth = w&3-ish role; covers both
    // 64-row halves (sv0/p0 = rows 0..63, sv1/p1 = rows 64..127, per-lane values).
    auto stage = [&](char* bufb, int sv0, int sv1, int p0, int p1) {
        ushort* bAh  = (ushort*)bufb;
        ushort* bAl  = (ushort*)(bufb + EBUF);
        int*    bDst = (int*)(bufb + 2*EBUF);
        if (w < 4) {
            #pragma unroll
            for (int g = 0; g < 4; ++g) {
                int kg = w*4 + g;
                gld16(xh + (size_t)sv0*IN_DIM + w*32 + g*8, &bAh[(kg*TILE +  0)*8]);
                gld16(xh + (size_t)sv1*IN_DIM + w*32 + g*8, &bAh[(kg*TILE + 64)*8]);
            }
            // edge_attr: w=0 eah/half0, w=1 eah/half1, w=2 eal/half0, w=3 eal/half1
            const ushort* es = (w & 2) ? eal : eah;
            ushort* bd       = (w & 2) ? bAl : bAh;
            int pp   = (w & 1) ? p1 : p0;
            int half = (w & 1) ? 64 : 0;
            gld16(es + (size_t)pp*EDGE_D + 0, &bd[(16*TILE + half)*8]);
            gld16(es + (size_t)pp*EDGE_D + 8, &bd[(17*TILE + half)*8]);
        } else {
            int cq = w - 4;
            #pragma unroll
            for (int g = 0; g < 4; ++g) {
                int kg = cq*4 + g;
                gld16(xl + (size_t)sv0*IN_DIM + cq*32 + g*8, &bAl[(kg*TILE +  0)*8]);
                gld16(xl + (size_t)sv1*IN_DIM + cq*32 + g*8, &bAl[(kg*TILE + 64)*8]);
            }
            if      (w == 4) gld4(dstS + p0, bDst);
            else if (w == 5) gld4(dstS + p1, bDst + 64);
        }
    };

    // ---- prologue ----
    const int t0 = blockIdx.x;
    {
        int p0 = t0 * TILE + lane, p1 = p0 + 64;
        stage(smem, srcS[p0], srcS[p1], p0, p1);
    }
    int sn0 = srcS[min((t0 + G) * TILE + lane,      nP - 1)];
    int sn1 = srcS[min((t0 + G) * TILE + 64 + lane, nP - 1)];
    __syncthreads();   // drains prologue DMA

    int cur = 0;
    for (int t = t0; t < nTiles; t += G) {
        char* bufc = smem + cur * EBUFSZ;
        char* bufn = smem + (cur ^ 1) * EBUFSZ;

        // ---- stage next tile (overlaps MFMA; drained at the barrier) ----
        if (t + G < nTiles) {
            int p0 = (t + G) * TILE + lane, p1 = p0 + 64;
            stage(bufn, sn0, sn1, p0, p1);
        }
        sn0 = srcS[min((t + 2*G) * TILE + lane,      nP - 1)];
        sn1 = srcS[min((t + 2*G) * TILE + 64 + lane, nP - 1)];

        const ushort* cAh  = (const ushort*)bufc;
        const ushort* cAl  = (const ushort*)(bufc + EBUF);
        const int*    cDst = (const int*)(bufc + 2*EBUF);

        f32x16 acc0, acc1;
        #pragma unroll
        for (int j = 0; j < 16; ++j) { acc0[j] = bv0; acc1[j] = bv1; }

        // ---- MFMA: 9 k-steps; one A hi/lo pair feeds 6 MFMAs (2 coltiles x 3) ----
        #pragma unroll
        for (int kg = 0; kg < 9; ++kg) {
            const int base = ((kg*2 + h) * TILE + rt*32 + cl) * 8;
            s16x8 ah = *(const s16x8*)&cAh[base];
            s16x8 al = *(const s16x8*)&cAl[base];
            acc0 = __builtin_amdgcn_mfma_f32_32x32x16_bf16(ah, Bh[kg][0], acc0, 0, 0, 0);
            acc1 = __builtin_amdgcn_mfma_f32_32x32x16_bf16(ah, Bh[kg][1], acc1, 0, 0, 0);
            acc0 = __builtin_amdgcn_mfma_f32_32x32x16_bf16(al, Bh[kg][0], acc0, 0, 0, 0);
            acc1 = __builtin_amdgcn_mfma_f32_32x32x16_bf16(al, Bh[kg][1], acc1, 0, 0, 0);
            acc0 = __builtin_amdgcn_mfma_f32_32x32x16_bf16(ah, Bl[kg][0], acc0, 0, 0, 0);
            acc1 = __builtin_amdgcn_mfma_f32_32x32x16_bf16(ah, Bl[kg][1], acc1, 0, 0, 0);
        }

        // ---- capture dst ids BEFORE the barrier (regs live across: ~50, fine at 256) ----
        int4 dd[4];
        #pragma unroll
        for (int q = 0; q < 4; ++q)
            dd[q] = *(const int4*)&cDst[rt*32 + q*8 + h*4];

        __syncthreads();   // drains next-tile DMA; closes reads of bufc

        // ---- POST-barrier lane-local segmented reduce over 16 consecutive sorted ----
        // ---- positions; emissions drain during NEXT tile (one full tile of slack) ----
        {
            float* aggc = agg + cg * 64 + cl;
            int cd = dd[0].x;
            float c0 = fmaxf(acc0[0], 0.0f);
            float c1 = fmaxf(acc1[0], 0.0f);
            bool firstRun = true;
            #pragma unroll
            for (int j = 1; j < 16; ++j) {
                const int d = ((const int*)&dd[j >> 2])[j & 3];
                const float u0 = fmaxf(acc0[j], 0.0f);
                const float u1 = fmaxf(acc1[j], 0.0f);
                if (d == cd) {
                    c0 += u0; c1 += u1;
                } else {
                    if (cd >= 0) {
                        if (firstRun) {
                            atomicAdd(aggc + (size_t)cd * N_OUT,      c0);
                            atomicAdd(aggc + (size_t)cd * N_OUT + 32, c1);
                        } else {
                            aggc[(size_t)cd * N_OUT]      = c0;
                            aggc[(size_t)cd * N_OUT + 32] = c1;
                        }
                    }
                    firstRun = false;
                    cd = d; c0 = u0; c1 = u1;
                }
            }
            if (cd >= 0) {
                atomicAdd(aggc + (size_t)cd * N_OUT,      c0);
                atomicAdd(aggc + (size_t)cd * N_OUT + 32, c1);
            }
        }

        cur ^= 1;
    }
}

// ---------------- node update (split-bf16 MFMA): relu(concat(h, agg/cnt) @ U) ----------------
__global__ __launch_bounds__(512, 2) void node_mfma_kernel(
    const ushort* __restrict__ hh, const ushort* __restrict__ hl,
    const float* __restrict__ agg, const float* __restrict__ cnt,
    const ushort* __restrict__ Uhf, const ushort* __restrict__ Ulf,
    float* __restrict__ outf, ushort* __restrict__ outh, ushort* __restrict__ outl,
    int lastLayer, int nNodes)
{
    __shared__ __align__(16) ushort sAh[NKG_N * TILE_N * 8];   // 32768 B
    __shared__ __align__(16) ushort sAl[NKG_N * TILE_N * 8];   // 32768 B

    const int tid  = threadIdx.x;
    const int w    = tid >> 6;
    const int lane = tid & 63;
    const int lg   = lane >> 4;
    const int lr   = lane & 15;
    const int col  = w * 16 + lr;
    const int tile = blockIdx.x;
    const int row  = lane;          // 0..63
    const int c    = w;             // 0..7 k-eighth

    s16x8 Bh[8], Bl[8];
    #pragma unroll
    for (int kb = 0; kb < 8; ++kb) {
        int kg = kb * 4 + lg;
        Bh[kb] = *(const s16x8*)&Uhf[(kg * N_OUT + col) * 8];
        Bl[kb] = *(const s16x8*)&Ulf[(kg * N_OUT + col) * 8];
    }

    const int ii = min(tile * TILE_N + row, nNodes - 1);
    if (c < 4) {   // h part: kg 0..15, pure DMA copy
        #pragma unroll
        for (int g = 0; g < 4; ++g) {
            int kg = c*4 + g;
            gld16(hh + (size_t)ii*N_OUT + c*32 + g*8, &sAh[(kg*TILE_N)*8]);
            gld16(hl + (size_t)ii*N_OUT + c*32 + g*8, &sAl[(kg*TILE_N)*8]);
        }
    } else {       // agg part: scale by 1/deg, split
        float rc = 1.0f / fmaxf(cnt[ii], 1.0f);
        const float4* pa = (const float4*)(agg + (size_t)ii*N_OUT + (c - 4)*32);
        #pragma unroll
        for (int g = 0; g < 4; ++g) {
            float4 v0 = pa[g*2], v1 = pa[g*2 + 1];
            float a[8] = {v0.x, v0.y, v0.z, v0.w, v1.x, v1.y, v1.z, v1.w};
            s16x8 hv, lv;
            #pragma unroll
            for (int j = 0; j < 8; ++j) {
                float f = a[j] * rc;
                ushort h = f2bf(f);
                hv[j] = (short)h;
                lv[j] = (short)f2bf(f - bf2f(h));
            }
            int kg = 16 + (c - 4)*4 + g;
            *(s16x8*)&sAh[(kg*TILE_N + row)*8] = hv;
            *(s16x8*)&sAl[(kg*TILE_N + row)*8] = lv;
        }
    }
    __syncthreads();

    f32x4 acc[4];
    #pragma unroll
    for (int b = 0; b < 4; ++b) acc[b] = (f32x4){0.f, 0.f, 0.f, 0.f};

    #pragma unroll
    for (int kb = 0; kb < 8; ++kb) {
        #pragma unroll
        for (int b = 0; b < 4; ++b) {
            const int base = ((kb*4 + lg) * TILE_N + b*16 + lr) * 8;
            s16x8 ah = *(const s16x8*)&sAh[base];
            s16x8 al = *(const s16x8*)&sAl[base];
            acc[b] = __builtin_amdgcn_mfma_f32_16x16x32_bf16(ah, Bh[kb], acc[b], 0, 0, 0);
            acc[b] = __builtin_amdgcn_mfma_f32_16x16x32_bf16(al, Bh[kb], acc[b], 0, 0, 0);
            acc[b] = __builtin_amdgcn_mfma_f32_16x16x32_bf16(ah, Bl[kb], acc[b], 0, 0, 0);
        }
    }

    #pragma unroll
    for (int b = 0; b < 4; ++b) {
        #pragma unroll
        for (int r = 0; r < 4; ++r) {
            int rr = tile * TILE_N + b*16 + lg*4 + r;
            if (rr < nNodes) {
                float v = fmaxf(acc[b][r], 0.0f);
                if (lastLayer) {
                    outf[(size_t)rr * N_OUT + col] = v;
                } else {
                    ushort h = f2bf(v);
                    outh[(size_t)rr * N_OUT + col] = h;
                    outl[(size_t)rr * N_OUT + col] = f2bf(v - bf2f(h));
                }
            }
        }
    }
}

extern "C" void kernel_launch(void* const* d_in, const int* in_sizes, int n_in,
                              void* d_out, int out_size, void* d_ws, size_t ws_size,
                              hipStream_t stream)
{
    const float* x  = (const float*)d_in[0];
    const int*   ei = (const int*)  d_in[1];
    const float* ea = (const float*)d_in[2];
    const float* W1 = (const float*)d_in[3];
    const float* b1 = (const float*)d_in[4];
    const float* U1 = (const float*)d_in[5];
    const float* W2 = (const float*)d_in[6];
    const float* b2 = (const float*)d_in[7];
    const float* U2 = (const float*)d_in[8];

    const int nE      = in_sizes[1] / 2;
    const int nNodes  = in_sizes[0] / IN_DIM;
    const int nTilesE = (nE + TILE - 1) / TILE;
    const int nP      = nTilesE * TILE;
    const int nTilesN = (nNodes + TILE_N - 1) / TILE_N;
    const int nSB     = (nNodes + 1023) / 1024;
    const int* srcp = ei;
    const int* dstp = ei + nE;

    char* p = (char*)d_ws;
    auto alloc = [&](size_t bytes) { void* r = (void*)p; p += (bytes + 255) & ~(size_t)255; return r; };

    float*  agg   = (float*) alloc((size_t)nNodes * N_OUT * sizeof(float));
    ushort* xhh   = (ushort*)alloc((size_t)nNodes * N_OUT * sizeof(ushort));
    ushort* xll   = (ushort*)alloc((size_t)nNodes * N_OUT * sizeof(ushort));
    float*  cntf  = (float*) alloc((size_t)nNodes * sizeof(float));
    int*    hist  = (int*)   alloc((size_t)nNodes * sizeof(int));
    int*    incl  = (int*)   alloc((size_t)nNodes * sizeof(int));
    int*    bsum  = (int*)   alloc((size_t)(nSB + 1) * sizeof(int));
    int*    rowptr= (int*)   alloc((size_t)(nNodes + 1) * sizeof(int));
    int*    cursor= (int*)   alloc((size_t)nNodes * sizeof(int));
    int*    eperm = (int*)   alloc((size_t)nP * sizeof(int));
    int*    dstS  = (int*)   alloc((size_t)nP * sizeof(int));
    int*    srcS  = (int*)   alloc((size_t)nP * sizeof(int));
    ushort* eah   = (ushort*)alloc((size_t)nP * EDGE_D * sizeof(ushort));
    ushort* eal   = (ushort*)alloc((size_t)nP * EDGE_D * sizeof(ushort));
    ushort* Whf1  = (ushort*)alloc((size_t)NKG_E * 8 * N_OUT * sizeof(ushort));
    ushort* Wlf1  = (ushort*)alloc((size_t)NKG_E * 8 * N_OUT * sizeof(ushort));
    ushort* Whf2  = (ushort*)alloc((size_t)NKG_E * 8 * N_OUT * sizeof(ushort));
    ushort* Wlf2  = (ushort*)alloc((size_t)NKG_E * 8 * N_OUT * sizeof(ushort));
    ushort* Uhf1  = (ushort*)alloc((size_t)NKG_N * 8 * N_OUT * sizeof(ushort));
    ushort* Ulf1  = (ushort*)alloc((size_t)NKG_N * 8 * N_OUT * sizeof(ushort));
    ushort* Uhf2  = (ushort*)alloc((size_t)NKG_N * 8 * N_OUT * sizeof(ushort));
    ushort* Ulf2  = (ushort*)alloc((size_t)NKG_N * 8 * N_OUT * sizeof(ushort));
    float*  outp  = (float*)d_out;

    // ---- one-time prep: CSR, permuted storage, degree, split ea/x, weight frags ----
    hipMemsetAsync(hist,   0,    (size_t)nNodes * sizeof(int), stream);
    hipMemsetAsync(cursor, 0,    (size_t)nNodes * sizeof(int), stream);
    hipMemsetAsync(srcS,   0,    (size_t)nP * sizeof(int), stream);       // pad: node 0
    hipMemsetAsync(dstS,   0xFF, (size_t)nP * sizeof(int), stream);       // pad: dst -1
    hist_kernel<<<(nE + 255)/256, 256, 0, stream>>>(dstp, hist, nE);
    scan1_kernel<<<nSB, 1024, 0, stream>>>(hist, incl, bsum, nNodes);
    scan2_kernel<<<1, 64, 0, stream>>>(bsum, nSB);
    scan3_kernel<<<(nNodes + 255)/256, 256, 0, stream>>>(incl, hist, bsum, rowptr, nNodes);
    scatter_kernel<<<(nE + 255)/256, 256, 0, stream>>>(srcp, dstp, rowptr, cursor,
                                                       eperm, srcS, dstS, nE);
    deg_kernel<<<(nNodes + 255)/256, 256, 0, stream>>>(hist, cntf, nNodes);
    eaprep_kernel<<<(2*nP + 255)/256, 256, 0, stream>>>(ea, eperm, eah, eal, nE, nP);
    wprep_kernel<<<(NKG_E*8*N_OUT + 255)/256, 256, 0, stream>>>(W1, Whf1, Wlf1, NKG_E*8);
    wprep_kernel<<<(NKG_E*8*N_OUT + 255)/256, 256, 0, stream>>>(W2, Whf2, Wlf2, NKG_E*8);
    wprep_kernel<<<(NKG_N*8*N_OUT + 255)/256, 256, 0, stream>>>(U1, Uhf1, Ulf1, NKG_N*8);
    wprep_kernel<<<(NKG_N*8*N_OUT + 255)/256, 256, 0, stream>>>(U2, Uhf2, Ulf2, NKG_N*8);
    split_kernel<<<((nNodes*N_OUT) + 255)/256, 256, 0, stream>>>(x, xhh, xll, nNodes * IN_DIM);

    auto run_layer = [&](const ushort* Whf, const ushort* Wlf, const float* b,
                         const ushort* Uhf, const ushort* Ulf, int last) {
        hipMemsetAsync(agg, 0, (size_t)nNodes * N_OUT * sizeof(float), stream);
        edge_mfma_kernel<<<256, 512, 0, stream>>>(xhh, xll, srcS, dstS, eah, eal,
                                                  Whf, Wlf, b, agg, nTilesE);
        node_mfma_kernel<<<nTilesN, 512, 0, stream>>>(xhh, xll, agg, cntf, Uhf, Ulf,
                                                      outp, xhh, xll, last, nNodes);
    };

    run_layer(Whf1, Wlf1, b1, Uhf1, Ulf1, 0);   // conv1 -> (xhh,xll)
    run_layer(Whf2, Wlf2, b2, Uhf2, Ulf2, 0);   // conv2 -> (xhh,xll)
    run_layer(Whf2, Wlf2, b2, Uhf2, Ulf2, 1);   // conv3 -> d_out (f32)
}

// Round 16
// 489.546 us; speedup vs baseline: 1.1986x; 1.1289x over previous
//
#include <hip/hip_runtime.h>

#define N_OUT   128
#define IN_DIM  128
#define EDGE_D  16
#define TILE    64
#define TILE_N  64
#define NKG_E   18    // edge kgroups of 8 k (144 exact)
#define NKG_N   32    // node kgroups (256 k)

#define EBUF    (NKG_E*TILE*16)        // 18432 B per sA half
#define EBUFSZ  (2*EBUF + TILE*4)      // 37120 B per buffer (sAh+sAl+sDst)

typedef short  s16x8  __attribute__((ext_vector_type(8)));
typedef float  f32x4  __attribute__((ext_vector_type(4)));

__device__ __forceinline__ ushort f2bf(float f) {
    unsigned u = __float_as_uint(f);
    return (ushort)((u + 0x7FFFu + ((u >> 16) & 1u)) >> 16);   // RNE
}
__device__ __forceinline__ float bf2f(ushort h) {
    return __uint_as_float(((unsigned)h) << 16);
}

// async global->LDS DMA: dest = wave-uniform LDS base + lane*size; src is per-lane
__device__ __forceinline__ void gld16(const void* g, void* l) {
    __builtin_amdgcn_global_load_lds((const __attribute__((address_space(1))) void*)g,
                                     (__attribute__((address_space(3))) void*)l, 16, 0, 0);
}
__device__ __forceinline__ void gld4(const void* g, void* l) {
    __builtin_amdgcn_global_load_lds((const __attribute__((address_space(1))) void*)g,
                                     (__attribute__((address_space(3))) void*)l, 4, 0, 0);
}

// sorted pos <-> storage slot within a 64-row tile: swap bits [5:4] <-> [3:2]
// (involution). Lane kgroup lg owns 16 CONSECUTIVE sorted positions:
// pos = lg*16 + b*4 + r <-> row = b*16 + lg*4 + r.
__device__ __forceinline__ int perm_slot(int pos) {
    int i = pos & 63;
    int s = (i & 3) | ((i & 0x30) >> 2) | ((i & 0x0C) << 2);
    return (pos & ~63) | s;
}

// ---------------- one-time prep ----------------
__global__ void split_kernel(const float* __restrict__ x, ushort* __restrict__ xh,
                             ushort* __restrict__ xl, int n) {
    int i = blockIdx.x * blockDim.x + threadIdx.x;
    if (i < n) {
        float f = x[i];
        ushort h = f2bf(f);
        xh[i] = h;
        xl[i] = f2bf(f - bf2f(h));
    }
}

// W [K][128] f32 -> hi/lo bf16 in MFMA B-frag layout: [(k/8)*128 + col]*8 + (k&7)
__global__ void wprep_kernel(const float* __restrict__ W, ushort* __restrict__ Whf,
                             ushort* __restrict__ Wlf, int K) {
    int i = blockIdx.x * blockDim.x + threadIdx.x;
    if (i >= K * N_OUT) return;
    int k = i >> 7, col = i & 127;
    float f = W[k * N_OUT + col];
    ushort h = f2bf(f);
    int d = ((k >> 3) * N_OUT + col) * 8 + (k & 7);
    Whf[d] = h;
    Wlf[d] = f2bf(f - bf2f(h));
}

// permuted + split edge_attr, indexed by STORAGE slot (pad slots -> zeros)
__global__ void eaprep_kernel(const float* __restrict__ ea, const int* __restrict__ eperm,
                              ushort* __restrict__ eah, ushort* __restrict__ eal,
                              int nE, int nP) {
    int t2 = blockIdx.x * blockDim.x + threadIdx.x;
    int s = t2 >> 1, half = t2 & 1;
    if (s >= nP) return;
    int p = perm_slot(s);   // involution: inverse == forward
    s16x8 hv = {0,0,0,0,0,0,0,0}, lv = {0,0,0,0,0,0,0,0};
    if (p < nE) {
        int e = eperm[s];
        const float4* src = (const float4*)(ea + (size_t)e * EDGE_D + half * 8);
        float4 v0 = src[0], v1 = src[1];
        float a[8] = {v0.x, v0.y, v0.z, v0.w, v1.x, v1.y, v1.z, v1.w};
        #pragma unroll
        for (int j = 0; j < 8; ++j) {
            ushort h = f2bf(a[j]);
            hv[j] = (short)h;
            lv[j] = (short)f2bf(a[j] - bf2f(h));
        }
    }
    *(s16x8*)(eah + (size_t)s * EDGE_D + half * 8) = hv;
    *(s16x8*)(eal + (size_t)s * EDGE_D + half * 8) = lv;
}

// ---------------- CSR build (once; src/dst are layer-invariant) ----------------
__global__ void hist_kernel(const int* __restrict__ dst, int* __restrict__ hist, int nE) {
    int e = blockIdx.x * blockDim.x + threadIdx.x;
    if (e < nE) atomicAdd(&hist[dst[e]], 1);
}

__global__ void scan1_kernel(const int* __restrict__ hist, int* __restrict__ incl,
                             int* __restrict__ bsum, int n) {
    __shared__ int buf[1024];
    int i = blockIdx.x * 1024 + threadIdx.x;
    int v = (i < n) ? hist[i] : 0;
    buf[threadIdx.x] = v;
    __syncthreads();
    for (int off = 1; off < 1024; off <<= 1) {
        int t = (threadIdx.x >= (unsigned)off) ? buf[threadIdx.x - off] : 0;
        __syncthreads();
        buf[threadIdx.x] += t;
        __syncthreads();
    }
    if (i < n) incl[i] = buf[threadIdx.x];
    if (threadIdx.x == 1023) bsum[blockIdx.x] = buf[1023];
}
__global__ void scan2_kernel(int* __restrict__ bsum, int nb) {
    if (threadIdx.x == 0 && blockIdx.x == 0) {
        int run = 0;
        for (int i = 0; i < nb; ++i) { int t = bsum[i]; bsum[i] = run; run += t; }
    }
}
__global__ void scan3_kernel(const int* __restrict__ incl, const int* __restrict__ hist,
                             const int* __restrict__ bsum, int* __restrict__ rowptr, int n) {
    int i = blockIdx.x * blockDim.x + threadIdx.x;
    if (i < n) rowptr[i] = incl[i] - hist[i] + bsum[i >> 10];   // exclusive
}

// writes edge data at PERMUTED storage slot (pad slots pre-filled by memset)
__global__ void scatter_kernel(const int* __restrict__ src, const int* __restrict__ dst,
                               const int* __restrict__ rowptr, int* __restrict__ cursor,
                               int* __restrict__ eperm, int* __restrict__ srcS,
                               int* __restrict__ dstS, int nE) {
    int e = blockIdx.x * blockDim.x + threadIdx.x;
    if (e < nE) {
        int d = dst[e];
        int pos = rowptr[d] + atomicAdd(&cursor[d], 1);
        int s = perm_slot(pos);
        eperm[s] = e;
        dstS[s]  = d;
        srcS[s]  = src[e];
    }
}

__global__ void deg_kernel(const int* __restrict__ hist, float* __restrict__ cntf, int n) {
    int i = blockIdx.x * blockDim.x + threadIdx.x;
    if (i < n) cntf[i] = (float)hist[i];
}

// ---------------- edge GEMM: r13 skinny waves (16col x 64row, ~60 VGPR) as TWO ----------------
// ---------------- independent 512-thread blocks/CU (74.2KB LDS each): barriers ----------------
// ---------------- decoupled, 4 waves/SIMD. DMA double-buffer, 1 barrier/tile.  ----------------
__global__ __launch_bounds__(512, 4) void edge_mfma_kernel(
    const ushort* __restrict__ xh, const ushort* __restrict__ xl,
    const int*   __restrict__ srcS,
    const int*   __restrict__ dstS,
    const ushort* __restrict__ eah, const ushort* __restrict__ eal,
    const ushort* __restrict__ Whf, const ushort* __restrict__ Wlf,
    const float* __restrict__ bias,
    float* __restrict__ agg,     // pre-zeroed
    int nTiles)
{
    __shared__ __align__(16) char smem[2 * EBUFSZ];   // 74240 B -> 2 blocks/CU

    const int tid  = threadIdx.x;
    const int w    = tid >> 6;        // 0..7: col group (cols w*16 .. w*16+15)
    const int lane = tid & 63;
    const int lg   = lane >> 4;
    const int lr   = lane & 15;
    const s16x8 z8 = {0,0,0,0,0,0,0,0};
    const int nP = nTiles * TILE;

    // B fragments: 5 kb x (hi,lo) x 4 VGPRs = 40 regs; kb=4 covers kg16,17 only
    s16x8 Bh[5], Bl[5];
    #pragma unroll
    for (int kb = 0; kb < 5; ++kb) {
        int kg = kb * 4 + lg;
        if (kg < NKG_E) {
            Bh[kb] = *(const s16x8*)&Whf[(kg * N_OUT + w*16 + lr) * 8];
            Bl[kb] = *(const s16x8*)&Wlf[(kg * N_OUT + w*16 + lr) * 8];
        } else {
            Bh[kb] = z8; Bl[kb] = z8;
        }
    }
    const float bv = bias[w*16 + lr];
    const int G = gridDim.x;

    // stage one 64-row tile into `bufb` via DMA: wave w handles one k-quarter
    // of xh (w<4) or xl (w>=4); waves 0-3 also stage ea kgroups; wave 4 dst.
    auto stage = [&](char* bufb, int sv, int p) {
        ushort* bAh  = (ushort*)bufb;
        ushort* bAl  = (ushort*)(bufb + EBUF);
        int*    bDst = (int*)(bufb + 2*EBUF);
        if (w < 4) {
            #pragma unroll
            for (int g = 0; g < 4; ++g) {
                int kg = w*4 + g;
                gld16(xh + (size_t)sv*IN_DIM + w*32 + g*8, &bAh[kg*TILE*8]);
            }
        } else {
            int wq = w - 4;
            #pragma unroll
            for (int g = 0; g < 4; ++g) {
                int kg = wq*4 + g;
                gld16(xl + (size_t)sv*IN_DIM + wq*32 + g*8, &bAl[kg*TILE*8]);
            }
        }
        if      (w == 0) gld16(eah + (size_t)p*EDGE_D,     &bAh[16*TILE*8]);
        else if (w == 1) gld16(eah + (size_t)p*EDGE_D + 8, &bAh[17*TILE*8]);
        else if (w == 2) gld16(eal + (size_t)p*EDGE_D,     &bAl[16*TILE*8]);
        else if (w == 3) gld16(eal + (size_t)p*EDGE_D + 8, &bAl[17*TILE*8]);
        else if (w == 4) gld4(dstS + p, bDst);
    };

    // ---- prologue ----
    const int t0 = blockIdx.x;
    {
        int p = t0 * TILE + lane;
        stage(smem, srcS[p], p);
    }
    int srcNext = srcS[min((t0 + G) * TILE + lane, nP - 1)];
    __syncthreads();   // drains prologue DMA

    int cur = 0;
    for (int t = t0; t < nTiles; t += G) {
        char* bufc = smem + cur * EBUFSZ;
        char* bufn = smem + (cur ^ 1) * EBUFSZ;

        // ---- stage next tile (overlaps MFMA; drained at the barrier) ----
        if (t + G < nTiles) stage(bufn, srcNext, (t + G) * TILE + lane);
        srcNext = srcS[min((t + 2*G) * TILE + lane, nP - 1)];

        const ushort* cAh  = (const ushort*)bufc;
        const ushort* cAl  = (const ushort*)(bufc + EBUF);
        const int*    cDst = (const int*)(bufc + 2*EBUF);

        f32x4 acc[4];
        #pragma unroll
        for (int b = 0; b < 4; ++b) acc[b] = (f32x4){bv, bv, bv, bv};

        #pragma unroll
        for (int kb = 0; kb < 4; ++kb) {
            #pragma unroll
            for (int b = 0; b < 4; ++b) {
                const int base = ((kb*4 + lg) * TILE + b*16 + lr) * 8;
                s16x8 ah = *(const s16x8*)&cAh[base];
                s16x8 al = *(const s16x8*)&cAl[base];
                acc[b] = __builtin_amdgcn_mfma_f32_16x16x32_bf16(ah, Bh[kb], acc[b], 0, 0, 0);
                acc[b] = __builtin_amdgcn_mfma_f32_16x16x32_bf16(al, Bh[kb], acc[b], 0, 0, 0);
                acc[b] = __builtin_amdgcn_mfma_f32_16x16x32_bf16(ah, Bl[kb], acc[b], 0, 0, 0);
            }
        }
        {   // kb = 4: lg<2 -> kg 16/17; lg>=2 -> zero frags (k144..159 don't exist)
            #pragma unroll
            for (int b = 0; b < 4; ++b) {
                const int base = ((16 + (lg & 1)) * TILE + b*16 + lr) * 8;
                s16x8 ah = *(const s16x8*)&cAh[base];
                s16x8 al = *(const s16x8*)&cAl[base];
                if (lg >= 2) { ah = z8; al = z8; }
                acc[b] = __builtin_amdgcn_mfma_f32_16x16x32_bf16(ah, Bh[4], acc[b], 0, 0, 0);
                acc[b] = __builtin_amdgcn_mfma_f32_16x16x32_bf16(al, Bh[4], acc[b], 0, 0, 0);
                acc[b] = __builtin_amdgcn_mfma_f32_16x16x32_bf16(ah, Bl[4], acc[b], 0, 0, 0);
            }
        }

        // ---- lane-local segmented reduce over 16 consecutive sorted positions ----
        // lane lg owns sorted pos lg*16 + b*4 + r = row b*16 + lg*4 + r (storage perm).
        // interior runs globally unique -> plain store; open ends -> atomicAdd
        {
            float* aggc = agg + w*16 + lr;
            int cd = -1; float c0 = 0.0f; bool firstRun = true;
            #pragma unroll
            for (int b = 0; b < 4; ++b) {
                int4 dd = *(const int4*)&cDst[b*16 + lg*4];
                int   ds4[4] = {dd.x, dd.y, dd.z, dd.w};
                float vv4[4] = {fmaxf(acc[b][0], 0.0f), fmaxf(acc[b][1], 0.0f),
                                fmaxf(acc[b][2], 0.0f), fmaxf(acc[b][3], 0.0f)};
                #pragma unroll
                for (int r = 0; r < 4; ++r) {
                    if (b == 0 && r == 0) { cd = ds4[0]; c0 = vv4[0]; continue; }
                    if (ds4[r] == cd) {
                        c0 += vv4[r];
                    } else {
                        if (cd >= 0) {
                            if (firstRun) atomicAdd(aggc + (size_t)cd * N_OUT, c0);
                            else          aggc[(size_t)cd * N_OUT] = c0;
                        }
                        firstRun = false;
                        cd = ds4[r]; c0 = vv4[r];
                    }
                }
            }
            if (cd >= 0) atomicAdd(aggc + (size_t)cd * N_OUT, c0);
        }

        __syncthreads();   // drains next-tile DMA + closes WAR on bufn
        cur ^= 1;
    }
}

// ---------------- node update (split-bf16 MFMA): relu(concat(h, agg/cnt) @ U) ----------------
// grid-stride persistent: U-frags loaded ONCE per block, reused across tiles
__global__ __launch_bounds__(512, 2) void node_mfma_kernel(
    const ushort* __restrict__ hh, const ushort* __restrict__ hl,
    const float* __restrict__ agg, const float* __restrict__ cnt,
    const ushort* __restrict__ Uhf, const ushort* __restrict__ Ulf,
    float* __restrict__ outf, ushort* __restrict__ outh, ushort* __restrict__ outl,
    int lastLayer, int nNodes, int nTiles)
{
    __shared__ __align__(16) ushort sAh[NKG_N * TILE_N * 8];   // 32768 B
    __shared__ __align__(16) ushort sAl[NKG_N * TILE_N * 8];   // 32768 B

    const int tid  = threadIdx.x;
    const int w    = tid >> 6;
    const int lane = tid & 63;
    const int lg   = lane >> 4;
    const int lr   = lane & 15;
    const int col  = w * 16 + lr;
    const int row  = lane;          // 0..63
    const int c    = w;             // 0..7 k-eighth

    s16x8 Bh[8], Bl[8];
    #pragma unroll
    for (int kb = 0; kb < 8; ++kb) {
        int kg = kb * 4 + lg;
        Bh[kb] = *(const s16x8*)&Uhf[(kg * N_OUT + col) * 8];
        Bl[kb] = *(const s16x8*)&Ulf[(kg * N_OUT + col) * 8];
    }

    for (int tile = blockIdx.x; tile < nTiles; tile += gridDim.x) {
        const int ii = min(tile * TILE_N + row, nNodes - 1);
        if (c < 4) {   // h part: kg 0..15, pure DMA copy
            #pragma unroll
            for (int g = 0; g < 4; ++g) {
                int kg = c*4 + g;
                gld16(hh + (size_t)ii*N_OUT + c*32 + g*8, &sAh[(kg*TILE_N)*8]);
                gld16(hl + (size_t)ii*N_OUT + c*32 + g*8, &sAl[(kg*TILE_N)*8]);
            }
        } else {       // agg part: scale by 1/deg, split
            float rc = 1.0f / fmaxf(cnt[ii], 1.0f);
            const float4* pa = (const float4*)(agg + (size_t)ii*N_OUT + (c - 4)*32);
            #pragma unroll
            for (int g = 0; g < 4; ++g) {
                float4 v0 = pa[g*2], v1 = pa[g*2 + 1];
                float a[8] = {v0.x, v0.y, v0.z, v0.w, v1.x, v1.y, v1.z, v1.w};
                s16x8 hv, lv;
                #pragma unroll
                for (int j = 0; j < 8; ++j) {
                    float f = a[j] * rc;
                    ushort h = f2bf(f);
                    hv[j] = (short)h;
                    lv[j] = (short)f2bf(f - bf2f(h));
                }
                int kg = 16 + (c - 4)*4 + g;
                *(s16x8*)&sAh[(kg*TILE_N + row)*8] = hv;
                *(s16x8*)&sAl[(kg*TILE_N + row)*8] = lv;
            }
        }
        __syncthreads();

        f32x4 acc[4];
        #pragma unroll
        for (int b = 0; b < 4; ++b) acc[b] = (f32x4){0.f, 0.f, 0.f, 0.f};

        #pragma unroll
        for (int kb = 0; kb < 8; ++kb) {
            #pragma unroll
            for (int b = 0; b < 4; ++b) {
                const int base = ((kb*4 + lg) * TILE_N + b*16 + lr) * 8;
                s16x8 ah = *(const s16x8*)&sAh[base];
                s16x8 al = *(const s16x8*)&sAl[base];
                acc[b] = __builtin_amdgcn_mfma_f32_16x16x32_bf16(ah, Bh[kb], acc[b], 0, 0, 0);
                acc[b] = __builtin_amdgcn_mfma_f32_16x16x32_bf16(al, Bh[kb], acc[b], 0, 0, 0);
                acc[b] = __builtin_amdgcn_mfma_f32_16x16x32_bf16(ah, Bl[kb], acc[b], 0, 0, 0);
            }
        }

        #pragma unroll
        for (int b = 0; b < 4; ++b) {
            #pragma unroll
            for (int r = 0; r < 4; ++r) {
                int rr = tile * TILE_N + b*16 + lg*4 + r;
                if (rr < nNodes) {
                    float v = fmaxf(acc[b][r], 0.0f);
                    if (lastLayer) {
                        outf[(size_t)rr * N_OUT + col] = v;
                    } else {
                        ushort h = f2bf(v);
                        outh[(size_t)rr * N_OUT + col] = h;
                        outl[(size_t)rr * N_OUT + col] = f2bf(v - bf2f(h));
                    }
                }
            }
        }
        __syncthreads();   // LDS WAR before next tile's staging
    }
}

extern "C" void kernel_launch(void* const* d_in, const int* in_sizes, int n_in,
                              void* d_out, int out_size, void* d_ws, size_t ws_size,
                              hipStream_t stream)
{
    const float* x  = (const float*)d_in[0];
    const int*   ei = (const int*)  d_in[1];
    const float* ea = (const float*)d_in[2];
    const float* W1 = (const float*)d_in[3];
    const float* b1 = (const float*)d_in[4];
    const float* U1 = (const float*)d_in[5];
    const float* W2 = (const float*)d_in[6];
    const float* b2 = (const float*)d_in[7];
    const float* U2 = (const float*)d_in[8];

    const int nE      = in_sizes[1] / 2;
    const int nNodes  = in_sizes[0] / IN_DIM;
    const int nTilesE = (nE + TILE - 1) / TILE;
    const int nP      = nTilesE * TILE;
    const int nTilesN = (nNodes + TILE_N - 1) / TILE_N;
    const int nSB     = (nNodes + 1023) / 1024;
    const int* srcp = ei;
    const int* dstp = ei + nE;

    char* p = (char*)d_ws;
    auto alloc = [&](size_t bytes) { void* r = (void*)p; p += (bytes + 255) & ~(size_t)255; return r; };

    float*  agg   = (float*) alloc((size_t)nNodes * N_OUT * sizeof(float));
    ushort* xhh   = (ushort*)alloc((size_t)nNodes * N_OUT * sizeof(ushort));
    ushort* xll   = (ushort*)alloc((size_t)nNodes * N_OUT * sizeof(ushort));
    float*  cntf  = (float*) alloc((size_t)nNodes * sizeof(float));
    int*    hist  = (int*)   alloc((size_t)nNodes * sizeof(int));
    int*    incl  = (int*)   alloc((size_t)nNodes * sizeof(int));
    int*    bsum  = (int*)   alloc((size_t)(nSB + 1) * sizeof(int));
    int*    rowptr= (int*)   alloc((size_t)(nNodes + 1) * sizeof(int));
    int*    cursor= (int*)   alloc((size_t)nNodes * sizeof(int));
    int*    eperm = (int*)   alloc((size_t)nP * sizeof(int));
    int*    dstS  = (int*)   alloc((size_t)nP * sizeof(int));
    int*    srcS  = (int*)   alloc((size_t)nP * sizeof(int));
    ushort* eah   = (ushort*)alloc((size_t)nP * EDGE_D * sizeof(ushort));
    ushort* eal   = (ushort*)alloc((size_t)nP * EDGE_D * sizeof(ushort));
    ushort* Whf1  = (ushort*)alloc((size_t)NKG_E * 8 * N_OUT * sizeof(ushort));
    ushort* Wlf1  = (ushort*)alloc((size_t)NKG_E * 8 * N_OUT * sizeof(ushort));
    ushort* Whf2  = (ushort*)alloc((size_t)NKG_E * 8 * N_OUT * sizeof(ushort));
    ushort* Wlf2  = (ushort*)alloc((size_t)NKG_E * 8 * N_OUT * sizeof(ushort));
    ushort* Uhf1  = (ushort*)alloc((size_t)NKG_N * 8 * N_OUT * sizeof(ushort));
    ushort* Ulf1  = (ushort*)alloc((size_t)NKG_N * 8 * N_OUT * sizeof(ushort));
    ushort* Uhf2  = (ushort*)alloc((size_t)NKG_N * 8 * N_OUT * sizeof(ushort));
    ushort* Ulf2  = (ushort*)alloc((size_t)NKG_N * 8 * N_OUT * sizeof(ushort));
    float*  outp  = (float*)d_out;

    // ---- one-time prep: CSR, permuted storage, degree, split ea/x, weight frags ----
    hipMemsetAsync(hist,   0,    (size_t)nNodes * sizeof(int), stream);
    hipMemsetAsync(cursor, 0,    (size_t)nNodes * sizeof(int), stream);
    hipMemsetAsync(srcS,   0,    (size_t)nP * sizeof(int), stream);       // pad: node 0
    hipMemsetAsync(dstS,   0xFF, (size_t)nP * sizeof(int), stream);       // pad: dst -1
    hist_kernel<<<(nE + 255)/256, 256, 0, stream>>>(dstp, hist, nE);
    scan1_kernel<<<nSB, 1024, 0, stream>>>(hist, incl, bsum, nNodes);
    scan2_kernel<<<1, 64, 0, stream>>>(bsum, nSB);
    scan3_kernel<<<(nNodes + 255)/256, 256, 0, stream>>>(incl, hist, bsum, rowptr, nNodes);
    scatter_kernel<<<(nE + 255)/256, 256, 0, stream>>>(srcp, dstp, rowptr, cursor,
                                                       eperm, srcS, dstS, nE);
    deg_kernel<<<(nNodes + 255)/256, 256, 0, stream>>>(hist, cntf, nNodes);
    eaprep_kernel<<<(2*nP + 255)/256, 256, 0, stream>>>(ea, eperm, eah, eal, nE, nP);
    wprep_kernel<<<(NKG_E*8*N_OUT + 255)/256, 256, 0, stream>>>(W1, Whf1, Wlf1, NKG_E*8);
    wprep_kernel<<<(NKG_E*8*N_OUT + 255)/256, 256, 0, stream>>>(W2, Whf2, Wlf2, NKG_E*8);
    wprep_kernel<<<(NKG_N*8*N_OUT + 255)/256, 256, 0, stream>>>(U1, Uhf1, Ulf1, NKG_N*8);
    wprep_kernel<<<(NKG_N*8*N_OUT + 255)/256, 256, 0, stream>>>(U2, Uhf2, Ulf2, NKG_N*8);
    split_kernel<<<((nNodes*N_OUT) + 255)/256, 256, 0, stream>>>(x, xhh, xll, nNodes * IN_DIM);

    auto run_layer = [&](const ushort* Whf, const ushort* Wlf, const float* b,
                         const ushort* Uhf, const ushort* Ulf, int last) {
        hipMemsetAsync(agg, 0, (size_t)nNodes * N_OUT * sizeof(float), stream);
        edge_mfma_kernel<<<512, 512, 0, stream>>>(xhh, xll, srcS, dstS, eah, eal,
                                                  Whf, Wlf, b, agg, nTilesE);
        node_mfma_kernel<<<304, 512, 0, stream>>>(xhh, xll, agg, cntf, Uhf, Ulf,
                                                  outp, xhh, xll, last, nNodes, nTilesN);
    };

    run_layer(Whf1, Wlf1, b1, Uhf1, Ulf1, 0);   // conv1 -> (xhh,xll)
    run_layer(Whf2, Wlf2, b2, Uhf2, Ulf2, 0);   // conv2 -> (xhh,xll)
    run_layer(Whf2, Wlf2, b2, Uhf2, Ulf2, 1);   // conv3 -> d_out (f32)
}

// Round 17
// 367.101 us; speedup vs baseline: 1.5983x; 1.3335x over previous
//
#include <hip/hip_runtime.h>

#define N_OUT   128
#define IN_DIM  128
#define EDGE_D  16
#define TILE    64
#define TILE_N  64
#define NKG_E   18    // edge kgroups of 8 k (144 exact)
#define NKG_N   32    // node kgroups (256 k)

#define EBUF    (NKG_E*TILE*16)        // 18432 B (single bf16 A)
#define EBUFSZ  (EBUF + TILE*4)        // 18688 B per buffer (sA + sDst)

typedef short  s16x8  __attribute__((ext_vector_type(8)));
typedef float  f32x4  __attribute__((ext_vector_type(4)));

__device__ __forceinline__ ushort f2bf(float f) {
    unsigned u = __float_as_uint(f);
    return (ushort)((u + 0x7FFFu + ((u >> 16) & 1u)) >> 16);   // RNE
}
__device__ __forceinline__ float bf2f(ushort h) {
    return __uint_as_float(((unsigned)h) << 16);
}

// async global->LDS DMA: dest = wave-uniform LDS base + lane*size; src is per-lane
__device__ __forceinline__ void gld16(const void* g, void* l) {
    __builtin_amdgcn_global_load_lds((const __attribute__((address_space(1))) void*)g,
                                     (__attribute__((address_space(3))) void*)l, 16, 0, 0);
}
__device__ __forceinline__ void gld4(const void* g, void* l) {
    __builtin_amdgcn_global_load_lds((const __attribute__((address_space(1))) void*)g,
                                     (__attribute__((address_space(3))) void*)l, 4, 0, 0);
}

// sorted pos <-> storage slot within a 64-row tile: swap bits [5:4] <-> [3:2]
// (involution). Lane kgroup lg owns 16 CONSECUTIVE sorted positions:
// pos = lg*16 + b*4 + r <-> row = b*16 + lg*4 + r.
__device__ __forceinline__ int perm_slot(int pos) {
    int i = pos & 63;
    int s = (i & 3) | ((i & 0x30) >> 2) | ((i & 0x0C) << 2);
    return (pos & ~63) | s;
}

// ---------------- one-time prep ----------------
__global__ void split_kernel(const float* __restrict__ x, ushort* __restrict__ xh, int n) {
    int i = blockIdx.x * blockDim.x + threadIdx.x;
    if (i < n) xh[i] = f2bf(x[i]);
}

// W [K][128] f32 -> hi/lo bf16 in MFMA B-frag layout: [(k/8)*128 + col]*8 + (k&7)
__global__ void wprep_kernel(const float* __restrict__ W, ushort* __restrict__ Whf,
                             ushort* __restrict__ Wlf, int K) {
    int i = blockIdx.x * blockDim.x + threadIdx.x;
    if (i >= K * N_OUT) return;
    int k = i >> 7, col = i & 127;
    float f = W[k * N_OUT + col];
    ushort h = f2bf(f);
    int d = ((k >> 3) * N_OUT + col) * 8 + (k & 7);
    Whf[d] = h;
    Wlf[d] = f2bf(f - bf2f(h));
}

// permuted edge_attr (single bf16), indexed by STORAGE slot (pad slots -> zeros)
__global__ void eaprep_kernel(const float* __restrict__ ea, const int* __restrict__ eperm,
                              ushort* __restrict__ eah, int nE, int nP) {
    int t2 = blockIdx.x * blockDim.x + threadIdx.x;
    int s = t2 >> 1, half = t2 & 1;
    if (s >= nP) return;
    int p = perm_slot(s);   // involution: inverse == forward
    s16x8 hv = {0,0,0,0,0,0,0,0};
    if (p < nE) {
        int e = eperm[s];
        const float4* src = (const float4*)(ea + (size_t)e * EDGE_D + half * 8);
        float4 v0 = src[0], v1 = src[1];
        float a[8] = {v0.x, v0.y, v0.z, v0.w, v1.x, v1.y, v1.z, v1.w};
        #pragma unroll
        for (int j = 0; j < 8; ++j) hv[j] = (short)f2bf(a[j]);
    }
    *(s16x8*)(eah + (size_t)s * EDGE_D + half * 8) = hv;
}

// ---------------- CSR build (once; src/dst are layer-invariant) ----------------
__global__ void hist_kernel(const int* __restrict__ dst, int* __restrict__ hist, int nE) {
    int e = blockIdx.x * blockDim.x + threadIdx.x;
    if (e < nE) atomicAdd(&hist[dst[e]], 1);
}

__global__ void scan1_kernel(const int* __restrict__ hist, int* __restrict__ incl,
                             int* __restrict__ bsum, int n) {
    __shared__ int buf[1024];
    int i = blockIdx.x * 1024 + threadIdx.x;
    int v = (i < n) ? hist[i] : 0;
    buf[threadIdx.x] = v;
    __syncthreads();
    for (int off = 1; off < 1024; off <<= 1) {
        int t = (threadIdx.x >= (unsigned)off) ? buf[threadIdx.x - off] : 0;
        __syncthreads();
        buf[threadIdx.x] += t;
        __syncthreads();
    }
    if (i < n) incl[i] = buf[threadIdx.x];
    if (threadIdx.x == 1023) bsum[blockIdx.x] = buf[1023];
}
__global__ void scan2_kernel(int* __restrict__ bsum, int nb) {
    if (threadIdx.x == 0 && blockIdx.x == 0) {
        int run = 0;
        for (int i = 0; i < nb; ++i) { int t = bsum[i]; bsum[i] = run; run += t; }
    }
}
__global__ void scan3_kernel(const int* __restrict__ incl, const int* __restrict__ hist,
                             const int* __restrict__ bsum, int* __restrict__ rowptr, int n) {
    int i = blockIdx.x * blockDim.x + threadIdx.x;
    if (i < n) rowptr[i] = incl[i] - hist[i] + bsum[i >> 10];   // exclusive
}

// writes edge data at PERMUTED storage slot (pad slots pre-filled by memset)
__global__ void scatter_kernel(const int* __restrict__ src, const int* __restrict__ dst,
                               const int* __restrict__ rowptr, int* __restrict__ cursor,
                               int* __restrict__ eperm, int* __restrict__ srcS,
                               int* __restrict__ dstS, int nE) {
    int e = blockIdx.x * blockDim.x + threadIdx.x;
    if (e < nE) {
        int d = dst[e];
        int pos = rowptr[d] + atomicAdd(&cursor[d], 1);
        int s = perm_slot(pos);
        eperm[s] = e;
        dstS[s]  = d;
        srcS[s]  = src[e];
    }
}

__global__ void deg_kernel(const int* __restrict__ hist, float* __restrict__ cntf, int n) {
    int i = blockIdx.x * blockDim.x + threadIdx.x;
    if (i < n) cntf[i] = (float)hist[i];
}

// ---------------- edge GEMM: M = bf16(A) x (Wh + Wl). A single bf16 -> LDS reads ----------------
// ---------------- halve (160 b128/tile), MFMA 40/wave, staging halves. 2 blocks/CU, ------------
// ---------------- DMA double-buffer, 1 barrier/tile, lane-local 16-pos reduce.   ----------------
__global__ __launch_bounds__(512, 4) void edge_mfma_kernel(
    const ushort* __restrict__ xh,
    const int*   __restrict__ srcS,
    const int*   __restrict__ dstS,
    const ushort* __restrict__ eah,
    const ushort* __restrict__ Whf, const ushort* __restrict__ Wlf,
    const float* __restrict__ bias,
    float* __restrict__ agg,     // pre-zeroed
    int nTiles)
{
    __shared__ __align__(16) char smem[2 * EBUFSZ];   // 37376 B

    const int tid  = threadIdx.x;
    const int w    = tid >> 6;        // 0..7: col group (cols w*16 .. w*16+15)
    const int lane = tid & 63;
    const int lg   = lane >> 4;
    const int lr   = lane & 15;
    const s16x8 z8 = {0,0,0,0,0,0,0,0};
    const int nP = nTiles * TILE;

    // B fragments: 5 kb x (hi,lo) x 4 VGPRs = 40 regs; kb=4 covers kg16,17 only
    s16x8 Bh[5], Bl[5];
    #pragma unroll
    for (int kb = 0; kb < 5; ++kb) {
        int kg = kb * 4 + lg;
        if (kg < NKG_E) {
            Bh[kb] = *(const s16x8*)&Whf[(kg * N_OUT + w*16 + lr) * 8];
            Bl[kb] = *(const s16x8*)&Wlf[(kg * N_OUT + w*16 + lr) * 8];
        } else {
            Bh[kb] = z8; Bl[kb] = z8;
        }
    }
    const float bv = bias[w*16 + lr];
    const int G = gridDim.x;

    // stage one 64-row tile via DMA: wave w stages x kgroups 2w, 2w+1;
    // wave 0/1 also stage ea kg16/17; wave 2 stages dst ids.
    auto stage = [&](char* bufb, int sv, int p) {
        ushort* bA   = (ushort*)bufb;
        int*    bDst = (int*)(bufb + EBUF);
        #pragma unroll
        for (int g = 0; g < 2; ++g) {
            int kg = 2*w + g;
            gld16(xh + (size_t)sv*IN_DIM + kg*8, &bA[kg*TILE*8]);
        }
        if      (w == 0) gld16(eah + (size_t)p*EDGE_D,     &bA[16*TILE*8]);
        else if (w == 1) gld16(eah + (size_t)p*EDGE_D + 8, &bA[17*TILE*8]);
        else if (w == 2) gld4(dstS + p, bDst);
    };

    // ---- prologue ----
    const int t0 = blockIdx.x;
    {
        int p = t0 * TILE + lane;
        stage(smem, srcS[p], p);
    }
    int srcNext = srcS[min((t0 + G) * TILE + lane, nP - 1)];
    __syncthreads();   // drains prologue DMA

    int cur = 0;
    for (int t = t0; t < nTiles; t += G) {
        char* bufc = smem + cur * EBUFSZ;
        char* bufn = smem + (cur ^ 1) * EBUFSZ;

        // ---- stage next tile (overlaps MFMA; drained at the barrier) ----
        if (t + G < nTiles) stage(bufn, srcNext, (t + G) * TILE + lane);
        srcNext = srcS[min((t + 2*G) * TILE + lane, nP - 1)];

        const ushort* cA   = (const ushort*)bufc;
        const int*    cDst = (const int*)(bufc + EBUF);

        f32x4 acc[4];
        #pragma unroll
        for (int b = 0; b < 4; ++b) acc[b] = (f32x4){bv, bv, bv, bv};

        #pragma unroll
        for (int kb = 0; kb < 4; ++kb) {
            #pragma unroll
            for (int b = 0; b < 4; ++b) {
                const int base = ((kb*4 + lg) * TILE + b*16 + lr) * 8;
                s16x8 ah = *(const s16x8*)&cA[base];
                acc[b] = __builtin_amdgcn_mfma_f32_16x16x32_bf16(ah, Bh[kb], acc[b], 0, 0, 0);
                acc[b] = __builtin_amdgcn_mfma_f32_16x16x32_bf16(ah, Bl[kb], acc[b], 0, 0, 0);
            }
        }
        {   // kb = 4: lg<2 -> kg 16/17; lg>=2 -> zero frags (k144..159 don't exist)
            #pragma unroll
            for (int b = 0; b < 4; ++b) {
                const int base = ((16 + (lg & 1)) * TILE + b*16 + lr) * 8;
                s16x8 ah = *(const s16x8*)&cA[base];
                if (lg >= 2) ah = z8;
                acc[b] = __builtin_amdgcn_mfma_f32_16x16x32_bf16(ah, Bh[4], acc[b], 0, 0, 0);
                acc[b] = __builtin_amdgcn_mfma_f32_16x16x32_bf16(ah, Bl[4], acc[b], 0, 0, 0);
            }
        }

        // ---- lane-local segmented reduce over 16 consecutive sorted positions ----
        // interior runs globally unique -> plain store; open ends -> atomicAdd
        {
            float* aggc = agg + w*16 + lr;
            int cd = -1; float c0 = 0.0f; bool firstRun = true;
            #pragma unroll
            for (int b = 0; b < 4; ++b) {
                int4 dd = *(const int4*)&cDst[b*16 + lg*4];
                int   ds4[4] = {dd.x, dd.y, dd.z, dd.w};
                float vv4[4] = {fmaxf(acc[b][0], 0.0f), fmaxf(acc[b][1], 0.0f),
                                fmaxf(acc[b][2], 0.0f), fmaxf(acc[b][3], 0.0f)};
                #pragma unroll
                for (int r = 0; r < 4; ++r) {
                    if (b == 0 && r == 0) { cd = ds4[0]; c0 = vv4[0]; continue; }
                    if (ds4[r] == cd) {
                        c0 += vv4[r];
                    } else {
                        if (cd >= 0) {
                            if (firstRun) atomicAdd(aggc + (size_t)cd * N_OUT, c0);
                            else          aggc[(size_t)cd * N_OUT] = c0;
                        }
                        firstRun = false;
                        cd = ds4[r]; c0 = vv4[r];
                    }
                }
            }
            if (cd >= 0) atomicAdd(aggc + (size_t)cd * N_OUT, c0);
        }

        __syncthreads();   // drains next-tile DMA + closes WAR on bufn
        cur ^= 1;
    }
}

// ---------------- node update: relu(concat(h, agg/cnt) @ (Uh+Ul)), A single bf16 ----------------
// grid-stride persistent: U-frags loaded ONCE per block
__global__ __launch_bounds__(512, 2) void node_mfma_kernel(
    const ushort* __restrict__ hh,
    const float* __restrict__ agg, const float* __restrict__ cnt,
    const ushort* __restrict__ Uhf, const ushort* __restrict__ Ulf,
    float* __restrict__ outf, ushort* __restrict__ outh,
    int lastLayer, int nNodes, int nTiles)
{
    __shared__ __align__(16) ushort sA[NKG_N * TILE_N * 8];   // 32768 B

    const int tid  = threadIdx.x;
    const int w    = tid >> 6;
    const int lane = tid & 63;
    const int lg   = lane >> 4;
    const int lr   = lane & 15;
    const int col  = w * 16 + lr;
    const int row  = lane;          // 0..63
    const int c    = w;             // 0..7 staging role

    s16x8 Bh[8], Bl[8];
    #pragma unroll
    for (int kb = 0; kb < 8; ++kb) {
        int kg = kb * 4 + lg;
        Bh[kb] = *(const s16x8*)&Uhf[(kg * N_OUT + col) * 8];
        Bl[kb] = *(const s16x8*)&Ulf[(kg * N_OUT + col) * 8];
    }

    for (int tile = blockIdx.x; tile < nTiles; tile += gridDim.x) {
        const int ii = min(tile * TILE_N + row, nNodes - 1);
        if (c < 4) {   // h part: kg 0..15, pure DMA copy
            #pragma unroll
            for (int g = 0; g < 4; ++g) {
                int kg = c*4 + g;
                gld16(hh + (size_t)ii*N_OUT + kg*8, &sA[(kg*TILE_N)*8]);
            }
        } else {       // agg part: scale by 1/deg, single bf16
            float rc = 1.0f / fmaxf(cnt[ii], 1.0f);
            const float4* pa = (const float4*)(agg + (size_t)ii*N_OUT + (c - 4)*32);
            #pragma unroll
            for (int g = 0; g < 4; ++g) {
                float4 v0 = pa[g*2], v1 = pa[g*2 + 1];
                float a[8] = {v0.x, v0.y, v0.z, v0.w, v1.x, v1.y, v1.z, v1.w};
                s16x8 hv;
                #pragma unroll
                for (int j = 0; j < 8; ++j) hv[j] = (short)f2bf(a[j] * rc);
                int kg = 16 + (c - 4)*4 + g;
                *(s16x8*)&sA[(kg*TILE_N + row)*8] = hv;
            }
        }
        __syncthreads();

        f32x4 acc[4];
        #pragma unroll
        for (int b = 0; b < 4; ++b) acc[b] = (f32x4){0.f, 0.f, 0.f, 0.f};

        #pragma unroll
        for (int kb = 0; kb < 8; ++kb) {
            #pragma unroll
            for (int b = 0; b < 4; ++b) {
                const int base = ((kb*4 + lg) * TILE_N + b*16 + lr) * 8;
                s16x8 ah = *(const s16x8*)&sA[base];
                acc[b] = __builtin_amdgcn_mfma_f32_16x16x32_bf16(ah, Bh[kb], acc[b], 0, 0, 0);
                acc[b] = __builtin_amdgcn_mfma_f32_16x16x32_bf16(ah, Bl[kb], acc[b], 0, 0, 0);
            }
        }

        #pragma unroll
        for (int b = 0; b < 4; ++b) {
            #pragma unroll
            for (int r = 0; r < 4; ++r) {
                int rr = tile * TILE_N + b*16 + lg*4 + r;
                if (rr < nNodes) {
                    float v = fmaxf(acc[b][r], 0.0f);
                    if (lastLayer) outf[(size_t)rr * N_OUT + col] = v;
                    else           outh[(size_t)rr * N_OUT + col] = f2bf(v);
                }
            }
        }
        __syncthreads();   // LDS WAR before next tile's staging
    }
}

extern "C" void kernel_launch(void* const* d_in, const int* in_sizes, int n_in,
                              void* d_out, int out_size, void* d_ws, size_t ws_size,
                              hipStream_t stream)
{
    const float* x  = (const float*)d_in[0];
    const int*   ei = (const int*)  d_in[1];
    const float* ea = (const float*)d_in[2];
    const float* W1 = (const float*)d_in[3];
    const float* b1 = (const float*)d_in[4];
    const float* U1 = (const float*)d_in[5];
    const float* W2 = (const float*)d_in[6];
    const float* b2 = (const float*)d_in[7];
    const float* U2 = (const float*)d_in[8];

    const int nE      = in_sizes[1] / 2;
    const int nNodes  = in_sizes[0] / IN_DIM;
    const int nTilesE = (nE + TILE - 1) / TILE;
    const int nP      = nTilesE * TILE;
    const int nTilesN = (nNodes + TILE_N - 1) / TILE_N;
    const int nSB     = (nNodes + 1023) / 1024;
    const int* srcp = ei;
    const int* dstp = ei + nE;

    char* p = (char*)d_ws;
    auto alloc = [&](size_t bytes) { void* r = (void*)p; p += (bytes + 255) & ~(size_t)255; return r; };

    float*  agg   = (float*) alloc((size_t)nNodes * N_OUT * sizeof(float));
    ushort* xhh   = (ushort*)alloc((size_t)nNodes * N_OUT * sizeof(ushort));
    float*  cntf  = (float*) alloc((size_t)nNodes * sizeof(float));
    int*    hist  = (int*)   alloc((size_t)nNodes * sizeof(int));
    int*    incl  = (int*)   alloc((size_t)nNodes * sizeof(int));
    int*    bsum  = (int*)   alloc((size_t)(nSB + 1) * sizeof(int));
    int*    rowptr= (int*)   alloc((size_t)(nNodes + 1) * sizeof(int));
    int*    cursor= (int*)   alloc((size_t)nNodes * sizeof(int));
    int*    eperm = (int*)   alloc((size_t)nP * sizeof(int));
    int*    dstS  = (int*)   alloc((size_t)nP * sizeof(int));
    int*    srcS  = (int*)   alloc((size_t)nP * sizeof(int));
    ushort* eah   = (ushort*)alloc((size_t)nP * EDGE_D * sizeof(ushort));
    ushort* Whf1  = (ushort*)alloc((size_t)NKG_E * 8 * N_OUT * sizeof(ushort));
    ushort* Wlf1  = (ushort*)alloc((size_t)NKG_E * 8 * N_OUT * sizeof(ushort));
    ushort* Whf2  = (ushort*)alloc((size_t)NKG_E * 8 * N_OUT * sizeof(ushort));
    ushort* Wlf2  = (ushort*)alloc((size_t)NKG_E * 8 * N_OUT * sizeof(ushort));
    ushort* Uhf1  = (ushort*)alloc((size_t)NKG_N * 8 * N_OUT * sizeof(ushort));
    ushort* Ulf1  = (ushort*)alloc((size_t)NKG_N * 8 * N_OUT * sizeof(ushort));
    ushort* Uhf2  = (ushort*)alloc((size_t)NKG_N * 8 * N_OUT * sizeof(ushort));
    ushort* Ulf2  = (ushort*)alloc((size_t)NKG_N * 8 * N_OUT * sizeof(ushort));
    float*  outp  = (float*)d_out;

    // ---- one-time prep: CSR, permuted storage, degree, bf16 ea/x, weight frags ----
    hipMemsetAsync(hist,   0,    (size_t)nNodes * sizeof(int), stream);
    hipMemsetAsync(cursor, 0,    (size_t)nNodes * sizeof(int), stream);
    hipMemsetAsync(srcS,   0,    (size_t)nP * sizeof(int), stream);       // pad: node 0
    hipMemsetAsync(dstS,   0xFF, (size_t)nP * sizeof(int), stream);       // pad: dst -1
    hist_kernel<<<(nE + 255)/256, 256, 0, stream>>>(dstp, hist, nE);
    scan1_kernel<<<nSB, 1024, 0, stream>>>(hist, incl, bsum, nNodes);
    scan2_kernel<<<1, 64, 0, stream>>>(bsum, nSB);
    scan3_kernel<<<(nNodes + 255)/256, 256, 0, stream>>>(incl, hist, bsum, rowptr, nNodes);
    scatter_kernel<<<(nE + 255)/256, 256, 0, stream>>>(srcp, dstp, rowptr, cursor,
                                                       eperm, srcS, dstS, nE);
    deg_kernel<<<(nNodes + 255)/256, 256, 0, stream>>>(hist, cntf, nNodes);
    eaprep_kernel<<<(2*nP + 255)/256, 256, 0, stream>>>(ea, eperm, eah, nE, nP);
    wprep_kernel<<<(NKG_E*8*N_OUT + 255)/256, 256, 0, stream>>>(W1, Whf1, Wlf1, NKG_E*8);
    wprep_kernel<<<(NKG_E*8*N_OUT + 255)/256, 256, 0, stream>>>(W2, Whf2, Wlf2, NKG_E*8);
    wprep_kernel<<<(NKG_N*8*N_OUT + 255)/256, 256, 0, stream>>>(U1, Uhf1, Ulf1, NKG_N*8);
    wprep_kernel<<<(NKG_N*8*N_OUT + 255)/256, 256, 0, stream>>>(U2, Uhf2, Ulf2, NKG_N*8);
    split_kernel<<<((nNodes*N_OUT) + 255)/256, 256, 0, stream>>>(x, xhh, nNodes * IN_DIM);

    auto run_layer = [&](const ushort* Whf, const ushort* Wlf, const float* b,
                         const ushort* Uhf, const ushort* Ulf, int last) {
        hipMemsetAsync(agg, 0, (size_t)nNodes * N_OUT * sizeof(float), stream);
        edge_mfma_kernel<<<512, 512, 0, stream>>>(xhh, srcS, dstS, eah,
                                                  Whf, Wlf, b, agg, nTilesE);
        node_mfma_kernel<<<304, 512, 0, stream>>>(xhh, agg, cntf, Uhf, Ulf,
                                                  outp, xhh, last, nNodes, nTilesN);
    };

    run_layer(Whf1, Wlf1, b1, Uhf1, Ulf1, 0);   // conv1 -> xhh
    run_layer(Whf2, Wlf2, b2, Uhf2, Ulf2, 0);   // conv2 -> xhh
    run_layer(Whf2, Wlf2, b2, Uhf2, Ulf2, 1);   // conv3 -> d_out (f32)
}